// Round 1
// baseline (1085.481 us; speedup 1.0000x reference)
//
#include <hip/hip_runtime.h>
#include <hip/hip_bf16.h>

// Problem constants (validated at runtime from in_sizes where cheap)
#define DMODEL 512   // D = H*DK = H*DV = 512

// ---------------------------------------------------------------------------
// Tiled fp32 GEMM: C[Mrows x 512] = A[Mrows x 512] @ W[512 x 512] + bias
// BM=BN=128, BK=16, 256 threads, 8x8 micro-tile per thread.
// ---------------------------------------------------------------------------
__global__ __launch_bounds__(256)
void gemm512(const float* __restrict__ A, const float* __restrict__ W,
             const float* __restrict__ bias, float* __restrict__ C, int Mrows) {
  __shared__ float As[16][132];   // +4 pad: keeps 16B alignment, breaks conflicts
  __shared__ float Bs[16][128];
  const int t  = threadIdx.x;
  const int tx = t & 15;
  const int ty = t >> 4;
  const int row0 = blockIdx.y * 128;
  const int col0 = blockIdx.x * 128;

  float acc[8][8] = {};

  for (int k0 = 0; k0 < DMODEL; k0 += 16) {
    // ---- stage A tile (128x16) and B tile (16x128), 2 float4 each per thread
#pragma unroll
    for (int i = 0; i < 2; ++i) {
      int idx = t + i * 256;                 // 0..511
      int arow = idx >> 2;                   // 0..127
      int akk  = (idx & 3) * 4;              // 0,4,8,12
      float4 av = make_float4(0.f, 0.f, 0.f, 0.f);
      if (row0 + arow < Mrows)
        av = *(const float4*)(A + (size_t)(row0 + arow) * DMODEL + k0 + akk);
      As[akk + 0][arow] = av.x;
      As[akk + 1][arow] = av.y;
      As[akk + 2][arow] = av.z;
      As[akk + 3][arow] = av.w;

      int brow = idx >> 5;                   // 0..15
      int bcol = (idx & 31) * 4;             // 0..124
      *(float4*)&Bs[brow][bcol] =
          *(const float4*)(W + (size_t)(k0 + brow) * DMODEL + col0 + bcol);
    }
    __syncthreads();

#pragma unroll
    for (int k = 0; k < 16; ++k) {
      float4 a0 = *(const float4*)&As[k][ty * 8];
      float4 a1 = *(const float4*)&As[k][ty * 8 + 4];
      float4 b0 = *(const float4*)&Bs[k][tx * 8];
      float4 b1 = *(const float4*)&Bs[k][tx * 8 + 4];
      float ra[8] = {a0.x, a0.y, a0.z, a0.w, a1.x, a1.y, a1.z, a1.w};
      float rb[8] = {b0.x, b0.y, b0.z, b0.w, b1.x, b1.y, b1.z, b1.w};
#pragma unroll
      for (int i = 0; i < 8; ++i)
#pragma unroll
        for (int j = 0; j < 8; ++j)
          acc[i][j] += ra[i] * rb[j];
    }
    __syncthreads();
  }

#pragma unroll
  for (int i = 0; i < 8; ++i) {
    int r = row0 + ty * 8 + i;
    if (r >= Mrows) break;
#pragma unroll
    for (int j = 0; j < 8; j += 4) {
      int c = col0 + tx * 8 + j;
      float4 o;
      o.x = acc[i][j + 0] + bias[c + 0];
      o.y = acc[i][j + 1] + bias[c + 1];
      o.z = acc[i][j + 2] + bias[c + 2];
      o.w = acc[i][j + 3] + bias[c + 3];
      *(float4*)(C + (size_t)r * DMODEL + c) = o;
    }
  }
}

// ---------------------------------------------------------------------------
// CSR build: histogram of receivers, exclusive scan, stable-ish fill
// ---------------------------------------------------------------------------
__global__ void hist_kernel(const int* __restrict__ recv, int* __restrict__ deg, int M_) {
  int m = blockIdx.x * 256 + threadIdx.x;
  if (m < M_) atomicAdd(&deg[recv[m]], 1);
}

__global__ __launch_bounds__(1024)
void scan_kernel(const int* __restrict__ deg, int* __restrict__ offs,
                 int* __restrict__ cursor, int n) {
  __shared__ int sdata[1024];
  __shared__ int s_run;
  const int t = threadIdx.x;
  if (t == 0) s_run = 0;
  __syncthreads();
  for (int base = 0; base < n; base += 1024) {
    int v = (base + t < n) ? deg[base + t] : 0;
    sdata[t] = v;
    __syncthreads();
    for (int off = 1; off < 1024; off <<= 1) {
      int x = 0;
      if (t >= off) x = sdata[t - off];
      __syncthreads();
      if (t >= off) sdata[t] += x;
      __syncthreads();
    }
    int incl = sdata[t];
    int runbase = s_run;
    __syncthreads();
    if (t == 1023) s_run = runbase + sdata[1023];
    if (base + t < n) {
      int excl = runbase + incl - v;
      offs[base + t] = excl;
      cursor[base + t] = excl;
    }
    __syncthreads();
  }
  if (t == 0) offs[n] = s_run;
}

__global__ void fill_kernel(const int* __restrict__ recv, int* __restrict__ cursor,
                            int* __restrict__ sorted, int M_) {
  int m = blockIdx.x * 256 + threadIdx.x;
  if (m < M_) {
    int pos = atomicAdd(&cursor[recv[m]], 1);
    sorted[pos] = m;
  }
}

// ---------------------------------------------------------------------------
// Fused edge attention + aggregate: one wave (64 lanes) per receiver node.
// Lane l holds elements l*8..l*8+7 of the 512-wide row; head = l>>3
// (8 lanes per 64-element head). Per-head dot via shfl_xor butterfly.
// Global max / +3 shift dropped: cancels exactly in the per-receiver
// normalization; zero-degree receivers produce 0 either way.
// ---------------------------------------------------------------------------
__global__ __launch_bounds__(256)
void attn_kernel(const float* __restrict__ Q, const float* __restrict__ K,
                 const float* __restrict__ V, const int* __restrict__ senders,
                 const int* __restrict__ sorted, const int* __restrict__ offs,
                 float* __restrict__ attbuf, float* __restrict__ agg, int n) {
  const int lane = threadIdx.x & 63;
  const int wid  = threadIdx.x >> 6;
  const int r = blockIdx.x * 4 + wid;
  if (r >= n) return;
  const int start = offs[r];
  const int end   = offs[r + 1];

  const float4 q0 = *(const float4*)(Q + (size_t)r * DMODEL + lane * 8);
  const float4 q1 = *(const float4*)(Q + (size_t)r * DMODEL + lane * 8 + 4);

  // pass 1: scores -> exp -> ssum (+ stash exp per sorted edge position)
  float ssum = 0.f;
  for (int e = start; e < end; ++e) {
    int m = sorted[e];
    int s = senders[m];
    const float4 k0 = *(const float4*)(K + (size_t)s * DMODEL + lane * 8);
    const float4 k1 = *(const float4*)(K + (size_t)s * DMODEL + lane * 8 + 4);
    float p = q0.x * k0.x + q0.y * k0.y + q0.z * k0.z + q0.w * k0.w
            + q1.x * k1.x + q1.y * k1.y + q1.z * k1.z + q1.w * k1.w;
    p += __shfl_xor(p, 1);
    p += __shfl_xor(p, 2);
    p += __shfl_xor(p, 4);          // all 8 lanes of head group hold the dot
    float w = expf(p * 0.125f);     // / sqrt(DK)=8
    ssum += w;                      // group-uniform
    if ((lane & 7) == 0) attbuf[(size_t)e * 8 + (lane >> 3)] = w;
  }
  const float inv = (end > start) ? 1.0f / ssum : 0.f;

  // pass 2: weighted V gather-accumulate
  float acc[8] = {};
  for (int e = start; e < end; ++e) {
    int m = sorted[e];
    int s = senders[m];
    float w = attbuf[(size_t)e * 8 + (lane >> 3)] * inv;
    const float4 v0 = *(const float4*)(V + (size_t)s * DMODEL + lane * 8);
    const float4 v1 = *(const float4*)(V + (size_t)s * DMODEL + lane * 8 + 4);
    acc[0] += w * v0.x; acc[1] += w * v0.y; acc[2] += w * v0.z; acc[3] += w * v0.w;
    acc[4] += w * v1.x; acc[5] += w * v1.y; acc[6] += w * v1.z; acc[7] += w * v1.w;
  }
  *(float4*)(agg + (size_t)r * DMODEL + lane * 8)     = make_float4(acc[0], acc[1], acc[2], acc[3]);
  *(float4*)(agg + (size_t)r * DMODEL + lane * 8 + 4) = make_float4(acc[4], acc[5], acc[6], acc[7]);
}

// ---------------------------------------------------------------------------
// Launch
// ---------------------------------------------------------------------------
extern "C" void kernel_launch(void* const* d_in, const int* in_sizes, int n_in,
                              void* d_out, int out_size, void* d_ws, size_t ws_size,
                              hipStream_t stream) {
  const float* x    = (const float*)d_in[0];
  const int*   eidx = (const int*)d_in[1];
  const float* Wk   = (const float*)d_in[2];
  const float* bk   = (const float*)d_in[3];
  const float* Wq   = (const float*)d_in[4];
  const float* bq   = (const float*)d_in[5];
  const float* Wv   = (const float*)d_in[6];
  const float* bv   = (const float*)d_in[7];
  const float* Wff  = (const float*)d_in[8];
  const float* bff  = (const float*)d_in[9];
  float* out = (float*)d_out;

  const int N_ = in_sizes[0] / DMODEL;   // 25000
  const int M_ = in_sizes[1] / 2;        // 150000
  const int* senders = eidx;             // edge_index[0]
  const int* recv    = eidx + M_;        // edge_index[1]

  // workspace layout (all fp32): Q | K | V | agg | att | int arrays
  float* ws   = (float*)d_ws;
  float* Qb   = ws;
  float* Kb   = Qb + (size_t)N_ * DMODEL;
  float* Vb   = Kb + (size_t)N_ * DMODEL;
  float* aggb = Vb + (size_t)N_ * DMODEL;
  float* attb = aggb + (size_t)N_ * DMODEL;
  int* deg    = (int*)(attb + (size_t)M_ * 8);
  int* offs   = deg + N_;
  int* cursor = offs + N_ + 1;
  int* sorted = cursor + N_;

  // CSR build (independent of GEMMs; same stream => ordered before attn)
  hipMemsetAsync(deg, 0, N_ * sizeof(int), stream);
  hist_kernel<<<(M_ + 255) / 256, 256, 0, stream>>>(recv, deg, M_);
  scan_kernel<<<1, 1024, 0, stream>>>(deg, offs, cursor, N_);
  fill_kernel<<<(M_ + 255) / 256, 256, 0, stream>>>(recv, cursor, sorted, M_);

  // projections
  dim3 ggrid(DMODEL / 128, (N_ + 127) / 128);
  gemm512<<<ggrid, 256, 0, stream>>>(x, Wk, bk, Kb, N_);
  gemm512<<<ggrid, 256, 0, stream>>>(x, Wq, bq, Qb, N_);
  gemm512<<<ggrid, 256, 0, stream>>>(x, Wv, bv, Vb, N_);

  // fused edge softmax + aggregate
  attn_kernel<<<(N_ + 3) / 4, 256, 0, stream>>>(Qb, Kb, Vb, senders, sorted, offs,
                                                attb, aggb, N_);

  // output projection
  gemm512<<<ggrid, 256, 0, stream>>>(aggb, Wff, bff, out, N_);
}

// Round 2
// 471.569 us; speedup vs baseline: 2.3018x; 2.3018x over previous
//
#include <hip/hip_runtime.h>
#include <hip/hip_bf16.h>

#define DMODEL 512   // D = H*DK = H*DV = 512

typedef __attribute__((ext_vector_type(8))) short bf16x8;
typedef __attribute__((ext_vector_type(4))) float f32x4;

__device__ inline void gload_lds16(const void* g, void* s) {
  __builtin_amdgcn_global_load_lds((const __attribute__((address_space(1))) void*)g,
                                   (__attribute__((address_space(3))) void*)s, 16, 0, 0);
}

// ---------------------------------------------------------------------------
// bf16 MFMA GEMM: C[Mrows x 512] = A_bf16[Mrows x 512] @ Wt_bf16^T + bias
// Wt is the TRANSPOSED weight (Wt[n][k] = W[k][n]) so both operands stage
// identically. 128x128 block tile, 4 waves, each wave 64x64 (4x4 MFMA tiles).
// LDS is in fragment order: subtile i (16 rows x 32 k) stored as lane-linear
// [quad][row][8k] so global_load_lds staging is lane-contiguous AND fragment
// reads are contiguous ds_read_b128 (conflict-free).
// ---------------------------------------------------------------------------
__global__ __launch_bounds__(256)
void gemm_bf16(const __hip_bfloat16* __restrict__ A, const __hip_bfloat16* __restrict__ Wt,
               const float* __restrict__ bias, float* __restrict__ C, int Mrows) {
  __shared__ __align__(16) short sA[16 * 512];   // 16 subtiles x 512 bf16 = 16 KB
  __shared__ __align__(16) short sB[16 * 512];
  const int t = threadIdx.x;
  const int lane = t & 63;
  const int wid = t >> 6;
  const int wrow = wid >> 1, wcol = wid & 1;
  const int row0 = blockIdx.y * 128;
  const int col0 = blockIdx.x * 128;
  const int l15 = lane & 15, lq = lane >> 4;

  f32x4 acc[4][4] = {};

  for (int k0 = 0; k0 < DMODEL; k0 += 64) {
    // stage: each wave issues 4 A-subtile + 4 B-subtile global_load_lds (16B/lane)
#pragma unroll
    for (int j = 0; j < 4; ++j) {
      int i = wid * 4 + j;              // subtile id 0..15: s = i>>3 (k-half), mt = i&7
      int mt = i & 7, s = i >> 3;
      int ak = k0 + s * 32 + lq * 8;
      int arow = row0 + mt * 16 + l15;
      arow = min(arow, Mrows - 1);      // clamp tail rows (garbage ok, never stored)
      gload_lds16(A + (size_t)arow * DMODEL + ak, &sA[i * 512]);
      int brow = col0 + mt * 16 + l15;  // output col = Wt row, always < 512
      gload_lds16(Wt + (size_t)brow * DMODEL + ak, &sB[i * 512]);
    }
    __syncthreads();

#pragma unroll
    for (int s = 0; s < 2; ++s) {
      bf16x8 af[4], bfr[4];
#pragma unroll
      for (int m = 0; m < 4; ++m)
        af[m] = *(const bf16x8*)&sA[(s * 8 + wrow * 4 + m) * 512 + lane * 8];
#pragma unroll
      for (int n = 0; n < 4; ++n)
        bfr[n] = *(const bf16x8*)&sB[(s * 8 + wcol * 4 + n) * 512 + lane * 8];
#pragma unroll
      for (int m = 0; m < 4; ++m)
#pragma unroll
        for (int n = 0; n < 4; ++n)
          acc[m][n] = __builtin_amdgcn_mfma_f32_16x16x32_bf16(af[m], bfr[n], acc[m][n], 0, 0, 0);
    }
    __syncthreads();
  }

  // epilogue: C/D layout col=lane&15, row=quad*4+reg  (m89-verified mapping)
#pragma unroll
  for (int m = 0; m < 4; ++m) {
#pragma unroll
    for (int n = 0; n < 4; ++n) {
      int col = col0 + wcol * 64 + n * 16 + l15;
      float bv = bias[col];
#pragma unroll
      for (int i = 0; i < 4; ++i) {
        int row = row0 + wrow * 64 + m * 16 + lq * 4 + i;
        if (row < Mrows)
          C[(size_t)row * DMODEL + col] = acc[m][n][i] + bv;
      }
    }
  }
}

// ---------------------------------------------------------------------------
// fp32 -> bf16 convert (x), grid-stride over float4
// ---------------------------------------------------------------------------
__global__ void cvt_kernel(const float* __restrict__ src, __hip_bfloat16* __restrict__ dst, int n) {
  int i = (blockIdx.x * 256 + threadIdx.x) * 4;
  if (i < n) {
    float4 v = *(const float4*)(src + i);
    union { ushort4 u; __hip_bfloat16 h[4]; } o;
    o.h[0] = __float2bfloat16(v.x);
    o.h[1] = __float2bfloat16(v.y);
    o.h[2] = __float2bfloat16(v.z);
    o.h[3] = __float2bfloat16(v.w);
    *(ushort4*)(dst + i) = o.u;
  }
}

// ---------------------------------------------------------------------------
// 512x512 weight transpose + convert, batched over 4 weights via blockIdx.z
// ---------------------------------------------------------------------------
__global__ __launch_bounds__(256)
void wt_kernel(const float* __restrict__ W0, const float* __restrict__ W1,
               const float* __restrict__ W2, const float* __restrict__ W3,
               __hip_bfloat16* __restrict__ T0, __hip_bfloat16* __restrict__ T1,
               __hip_bfloat16* __restrict__ T2, __hip_bfloat16* __restrict__ T3) {
  const float* W; __hip_bfloat16* T;
  switch (blockIdx.z) {
    case 0: W = W0; T = T0; break;
    case 1: W = W1; T = T1; break;
    case 2: W = W2; T = T2; break;
    default: W = W3; T = T3; break;
  }
  __shared__ float tile[64][65];
  const int kb = blockIdx.y * 64, nb = blockIdx.x * 64;
  const int tx = threadIdx.x & 63, ty = threadIdx.x >> 6;
  for (int r = ty; r < 64; r += 4)
    tile[r][tx] = W[(size_t)(kb + r) * DMODEL + nb + tx];
  __syncthreads();
  for (int r = ty; r < 64; r += 4)
    T[(size_t)(nb + r) * DMODEL + kb + tx] = __float2bfloat16(tile[tx][r]);
}

// ---------------------------------------------------------------------------
// CSR build: histogram, single-block scan, fill
// ---------------------------------------------------------------------------
__global__ void hist_kernel(const int* __restrict__ recv, int* __restrict__ deg, int M_) {
  int m = blockIdx.x * 256 + threadIdx.x;
  if (m < M_) atomicAdd(&deg[recv[m]], 1);
}

__global__ __launch_bounds__(1024)
void scan_kernel(const int* __restrict__ deg, int* __restrict__ offs,
                 int* __restrict__ cursor, int n) {
  __shared__ int sdata[1024];
  __shared__ int s_run;
  const int t = threadIdx.x;
  if (t == 0) s_run = 0;
  __syncthreads();
  for (int base = 0; base < n; base += 1024) {
    int v = (base + t < n) ? deg[base + t] : 0;
    sdata[t] = v;
    __syncthreads();
    for (int off = 1; off < 1024; off <<= 1) {
      int x = 0;
      if (t >= off) x = sdata[t - off];
      __syncthreads();
      if (t >= off) sdata[t] += x;
      __syncthreads();
    }
    int incl = sdata[t];
    int runbase = s_run;
    __syncthreads();
    if (t == 1023) s_run = runbase + sdata[1023];
    if (base + t < n) {
      int excl = runbase + incl - v;
      offs[base + t] = excl;
      cursor[base + t] = excl;
    }
    __syncthreads();
  }
  if (t == 0) offs[n] = s_run;
}

__global__ void fill_kernel(const int* __restrict__ recv, int* __restrict__ cursor,
                            int* __restrict__ sorted, int M_) {
  int m = blockIdx.x * 256 + threadIdx.x;
  if (m < M_) {
    int pos = atomicAdd(&cursor[recv[m]], 1);
    sorted[pos] = m;
  }
}

// ---------------------------------------------------------------------------
// Fused edge attention + aggregate: one wave per receiver node.
// Q/K/V fp32; agg written directly as bf16 (input to final MFMA GEMM).
// Global max / +3 shift dropped: cancels exactly in per-receiver normalization.
// ---------------------------------------------------------------------------
__global__ __launch_bounds__(256)
void attn_kernel(const float* __restrict__ Q, const float* __restrict__ K,
                 const float* __restrict__ V, const int* __restrict__ senders,
                 const int* __restrict__ sorted, const int* __restrict__ offs,
                 float* __restrict__ attbuf, __hip_bfloat16* __restrict__ agg, int n) {
  const int lane = threadIdx.x & 63;
  const int wid  = threadIdx.x >> 6;
  const int r = blockIdx.x * 4 + wid;
  if (r >= n) return;
  const int start = offs[r];
  const int end   = offs[r + 1];

  const float4 q0 = *(const float4*)(Q + (size_t)r * DMODEL + lane * 8);
  const float4 q1 = *(const float4*)(Q + (size_t)r * DMODEL + lane * 8 + 4);

  float ssum = 0.f;
  for (int e = start; e < end; ++e) {
    int m = sorted[e];
    int s = senders[m];
    const float4 k0 = *(const float4*)(K + (size_t)s * DMODEL + lane * 8);
    const float4 k1 = *(const float4*)(K + (size_t)s * DMODEL + lane * 8 + 4);
    float p = q0.x * k0.x + q0.y * k0.y + q0.z * k0.z + q0.w * k0.w
            + q1.x * k1.x + q1.y * k1.y + q1.z * k1.z + q1.w * k1.w;
    p += __shfl_xor(p, 1);
    p += __shfl_xor(p, 2);
    p += __shfl_xor(p, 4);          // 8-lane head group all hold the dot
    float w = expf(p * 0.125f);     // 1/sqrt(DK)
    ssum += w;
    if ((lane & 7) == 0) attbuf[(size_t)e * 8 + (lane >> 3)] = w;
  }
  const float inv = (end > start) ? 1.0f / ssum : 0.f;

  float acc[8] = {};
  for (int e = start; e < end; ++e) {
    int m = sorted[e];
    int s = senders[m];
    float w = attbuf[(size_t)e * 8 + (lane >> 3)] * inv;
    const float4 v0 = *(const float4*)(V + (size_t)s * DMODEL + lane * 8);
    const float4 v1 = *(const float4*)(V + (size_t)s * DMODEL + lane * 8 + 4);
    acc[0] += w * v0.x; acc[1] += w * v0.y; acc[2] += w * v0.z; acc[3] += w * v0.w;
    acc[4] += w * v1.x; acc[5] += w * v1.y; acc[6] += w * v1.z; acc[7] += w * v1.w;
  }
  union { ushort4 u; __hip_bfloat16 h[4]; } o0, o1;
  o0.h[0] = __float2bfloat16(acc[0]); o0.h[1] = __float2bfloat16(acc[1]);
  o0.h[2] = __float2bfloat16(acc[2]); o0.h[3] = __float2bfloat16(acc[3]);
  o1.h[0] = __float2bfloat16(acc[4]); o1.h[1] = __float2bfloat16(acc[5]);
  o1.h[2] = __float2bfloat16(acc[6]); o1.h[3] = __float2bfloat16(acc[7]);
  *(ushort4*)(agg + (size_t)r * DMODEL + lane * 8)     = o0.u;
  *(ushort4*)(agg + (size_t)r * DMODEL + lane * 8 + 4) = o1.u;
}

// ---------------------------------------------------------------------------
// Launch
// ---------------------------------------------------------------------------
extern "C" void kernel_launch(void* const* d_in, const int* in_sizes, int n_in,
                              void* d_out, int out_size, void* d_ws, size_t ws_size,
                              hipStream_t stream) {
  const float* x    = (const float*)d_in[0];
  const int*   eidx = (const int*)d_in[1];
  const float* Wk   = (const float*)d_in[2];
  const float* bk   = (const float*)d_in[3];
  const float* Wq   = (const float*)d_in[4];
  const float* bq   = (const float*)d_in[5];
  const float* Wv   = (const float*)d_in[6];
  const float* bv   = (const float*)d_in[7];
  const float* Wff  = (const float*)d_in[8];
  const float* bff  = (const float*)d_in[9];
  float* out = (float*)d_out;

  const int N_ = in_sizes[0] / DMODEL;   // 25000
  const int M_ = in_sizes[1] / 2;        // 150000
  const int* senders = eidx;             // edge_index[0]
  const int* recv    = eidx + M_;        // edge_index[1]

  // workspace layout: fp32 Q|K|V|att, then bf16 x|agg|Wt[4], then ints (~213 MB)
  float* ws   = (float*)d_ws;
  float* Qb   = ws;
  float* Kb   = Qb + (size_t)N_ * DMODEL;
  float* Vb   = Kb + (size_t)N_ * DMODEL;
  float* attb = Vb + (size_t)N_ * DMODEL;
  __hip_bfloat16* xb   = (__hip_bfloat16*)(attb + (size_t)M_ * 8);
  __hip_bfloat16* aggb = xb + (size_t)N_ * DMODEL;
  __hip_bfloat16* Wtk  = aggb + (size_t)N_ * DMODEL;
  __hip_bfloat16* Wtq  = Wtk + DMODEL * DMODEL;
  __hip_bfloat16* Wtv  = Wtq + DMODEL * DMODEL;
  __hip_bfloat16* Wtff = Wtv + DMODEL * DMODEL;
  int* deg    = (int*)(Wtff + DMODEL * DMODEL);
  int* offs   = deg + N_;
  int* cursor = offs + N_ + 1;
  int* sorted = cursor + N_;

  // conversions
  int nx = N_ * DMODEL;
  cvt_kernel<<<(nx / 4 + 255) / 256, 256, 0, stream>>>(x, xb, nx);
  wt_kernel<<<dim3(8, 8, 4), 256, 0, stream>>>(Wk, Wq, Wv, Wff, Wtk, Wtq, Wtv, Wtff);

  // CSR build
  hipMemsetAsync(deg, 0, N_ * sizeof(int), stream);
  hist_kernel<<<(M_ + 255) / 256, 256, 0, stream>>>(recv, deg, M_);
  scan_kernel<<<1, 1024, 0, stream>>>(deg, offs, cursor, N_);
  fill_kernel<<<(M_ + 255) / 256, 256, 0, stream>>>(recv, cursor, sorted, M_);

  // projections (bf16 MFMA)
  dim3 ggrid(DMODEL / 128, (N_ + 127) / 128);
  gemm_bf16<<<ggrid, 256, 0, stream>>>(xb, Wtk, bk, Kb, N_);
  gemm_bf16<<<ggrid, 256, 0, stream>>>(xb, Wtq, bq, Qb, N_);
  gemm_bf16<<<ggrid, 256, 0, stream>>>(xb, Wtv, bv, Vb, N_);

  // fused edge softmax + aggregate (writes bf16 agg)
  attn_kernel<<<(N_ + 3) / 4, 256, 0, stream>>>(Qb, Kb, Vb, senders, sorted, offs,
                                                attb, aggb, N_);

  // output projection
  gemm_bf16<<<ggrid, 256, 0, stream>>>(aggb, Wtff, bff, out, N_);
}

// Round 3
// 401.601 us; speedup vs baseline: 2.7029x; 1.1742x over previous
//
#include <hip/hip_runtime.h>
#include <hip/hip_bf16.h>

#define DMODEL 512   // D = H*DK = H*DV = 512

typedef __attribute__((ext_vector_type(8))) short bf16x8;
typedef __attribute__((ext_vector_type(4))) float f32x4;

__device__ inline void gload_lds16(const void* g, void* s) {
  __builtin_amdgcn_global_load_lds((const __attribute__((address_space(1))) void*)g,
                                   (__attribute__((address_space(3))) void*)s, 16, 0, 0);
}

__device__ inline float bflo(unsigned u) {  // low bf16 of a packed uint -> float
  union { float f; unsigned u; } c; c.u = u << 16; return c.f;
}
__device__ inline float bfhi(unsigned u) {  // high bf16 -> float
  union { float f; unsigned u; } c; c.u = u & 0xffff0000u; return c.f;
}

// ---------------------------------------------------------------------------
// bf16 MFMA GEMM: C[Mrows x 512] = A_bf16 @ Wt_bf16^T + bias.
// OUT_BF16: write bf16 (Q/K/V path) vs fp32 (final output).
// 128x128 tile, 4 waves, 4x4 16x16x32 MFMA per wave, global_load_lds width=16,
// LDS in fragment order (lane-linear subtiles) -> conflict-free ds_read_b128.
// ---------------------------------------------------------------------------
template <bool OUT_BF16>
__global__ __launch_bounds__(256)
void gemm_bf16(const __hip_bfloat16* __restrict__ A, const __hip_bfloat16* __restrict__ Wt,
               const float* __restrict__ bias, void* __restrict__ Cv, int Mrows) {
  __shared__ __align__(16) short sA[16 * 512];
  __shared__ __align__(16) short sB[16 * 512];
  const int t = threadIdx.x;
  const int lane = t & 63;
  const int wid = t >> 6;
  const int wrow = wid >> 1, wcol = wid & 1;
  const int row0 = blockIdx.y * 128;
  const int col0 = blockIdx.x * 128;
  const int l15 = lane & 15, lq = lane >> 4;

  f32x4 acc[4][4] = {};

  for (int k0 = 0; k0 < DMODEL; k0 += 64) {
#pragma unroll
    for (int j = 0; j < 4; ++j) {
      int i = wid * 4 + j;
      int mt = i & 7, s = i >> 3;
      int ak = k0 + s * 32 + lq * 8;
      int arow = row0 + mt * 16 + l15;
      arow = min(arow, Mrows - 1);
      gload_lds16(A + (size_t)arow * DMODEL + ak, &sA[i * 512]);
      int brow = col0 + mt * 16 + l15;
      gload_lds16(Wt + (size_t)brow * DMODEL + ak, &sB[i * 512]);
    }
    __syncthreads();

#pragma unroll
    for (int s = 0; s < 2; ++s) {
      bf16x8 af[4], bfr[4];
#pragma unroll
      for (int m = 0; m < 4; ++m)
        af[m] = *(const bf16x8*)&sA[(s * 8 + wrow * 4 + m) * 512 + lane * 8];
#pragma unroll
      for (int n = 0; n < 4; ++n)
        bfr[n] = *(const bf16x8*)&sB[(s * 8 + wcol * 4 + n) * 512 + lane * 8];
#pragma unroll
      for (int m = 0; m < 4; ++m)
#pragma unroll
        for (int n = 0; n < 4; ++n)
          acc[m][n] = __builtin_amdgcn_mfma_f32_16x16x32_bf16(af[m], bfr[n], acc[m][n], 0, 0, 0);
    }
    __syncthreads();
  }

  // epilogue: C/D layout col=lane&15, row=quad*4+reg
#pragma unroll
  for (int m = 0; m < 4; ++m) {
#pragma unroll
    for (int n = 0; n < 4; ++n) {
      int col = col0 + wcol * 64 + n * 16 + l15;
      float bv = bias[col];
#pragma unroll
      for (int i = 0; i < 4; ++i) {
        int row = row0 + wrow * 64 + m * 16 + lq * 4 + i;
        if (row < Mrows) {
          float v = acc[m][n][i] + bv;
          if (OUT_BF16)
            ((__hip_bfloat16*)Cv)[(size_t)row * DMODEL + col] = __float2bfloat16(v);
          else
            ((float*)Cv)[(size_t)row * DMODEL + col] = v;
        }
      }
    }
  }
}

// ---------------------------------------------------------------------------
// fp32 -> bf16 convert (x)
// ---------------------------------------------------------------------------
__global__ void cvt_kernel(const float* __restrict__ src, __hip_bfloat16* __restrict__ dst, int n) {
  int i = (blockIdx.x * 256 + threadIdx.x) * 4;
  if (i < n) {
    float4 v = *(const float4*)(src + i);
    union { ushort4 u; __hip_bfloat16 h[4]; } o;
    o.h[0] = __float2bfloat16(v.x);
    o.h[1] = __float2bfloat16(v.y);
    o.h[2] = __float2bfloat16(v.z);
    o.h[3] = __float2bfloat16(v.w);
    *(ushort4*)(dst + i) = o.u;
  }
}

// ---------------------------------------------------------------------------
// 512x512 weight transpose + convert, batched over 4 weights via blockIdx.z
// ---------------------------------------------------------------------------
__global__ __launch_bounds__(256)
void wt_kernel(const float* __restrict__ W0, const float* __restrict__ W1,
               const float* __restrict__ W2, const float* __restrict__ W3,
               __hip_bfloat16* __restrict__ T0, __hip_bfloat16* __restrict__ T1,
               __hip_bfloat16* __restrict__ T2, __hip_bfloat16* __restrict__ T3) {
  const float* W; __hip_bfloat16* T;
  switch (blockIdx.z) {
    case 0: W = W0; T = T0; break;
    case 1: W = W1; T = T1; break;
    case 2: W = W2; T = T2; break;
    default: W = W3; T = T3; break;
  }
  __shared__ float tile[64][65];
  const int kb = blockIdx.y * 64, nb = blockIdx.x * 64;
  const int tx = threadIdx.x & 63, ty = threadIdx.x >> 6;
  for (int r = ty; r < 64; r += 4)
    tile[r][tx] = W[(size_t)(kb + r) * DMODEL + nb + tx];
  __syncthreads();
  for (int r = ty; r < 64; r += 4)
    T[(size_t)(nb + r) * DMODEL + kb + tx] = __float2bfloat16(tile[tx][r]);
}

// ---------------------------------------------------------------------------
// CSR build: histogram + parallel 3-phase scan + fill
// ---------------------------------------------------------------------------
__global__ void hist_kernel(const int* __restrict__ recv, int* __restrict__ deg, int M_) {
  int m = blockIdx.x * 256 + threadIdx.x;
  if (m < M_) atomicAdd(&deg[recv[m]], 1);
}

// phase 1: each block scans 1024 elements (256 thr x 4), writes local-exclusive
// offsets + per-block total
__global__ __launch_bounds__(256)
void scan_block(const int* __restrict__ deg, int* __restrict__ offs,
                int* __restrict__ bsum, int n) {
  __shared__ int sd[256];
  const int t = threadIdx.x;
  const int base = blockIdx.x * 1024;
  int v[4], s = 0;
#pragma unroll
  for (int j = 0; j < 4; ++j) {
    int idx = base + t * 4 + j;
    v[j] = (idx < n) ? deg[idx] : 0;
    s += v[j];
  }
  sd[t] = s;
  __syncthreads();
  for (int off = 1; off < 256; off <<= 1) {
    int x = (t >= off) ? sd[t - off] : 0;
    __syncthreads();
    sd[t] += x;
    __syncthreads();
  }
  int run = sd[t] - s;   // exclusive prefix of this thread's chunk
#pragma unroll
  for (int j = 0; j < 4; ++j) {
    int idx = base + t * 4 + j;
    if (idx < n) offs[idx] = run;
    run += v[j];
  }
  if (t == 255) bsum[blockIdx.x] = sd[255];
}

// phase 2: one wave scans the (<=64) block sums, writes exclusive bases + total
__global__ void scan_mid(const int* __restrict__ bsum, int* __restrict__ bbase,
                         int nb, int* __restrict__ offs, int n) {
  int t = threadIdx.x;
  int x = (t < nb) ? bsum[t] : 0;
  int v = x;
  for (int off = 1; off < 64; off <<= 1) {
    int y = __shfl_up(v, off);
    if (t >= off) v += y;
  }
  if (t < nb) bbase[t] = v - x;
  if (t == nb - 1) offs[n] = v;
}

// phase 3: add block base; also init cursor
__global__ void scan_add(int* __restrict__ offs, const int* __restrict__ bbase,
                         int* __restrict__ cursor, int n) {
  int i = blockIdx.x * 256 + threadIdx.x;
  if (i < n) {
    int o = offs[i] + bbase[i >> 10];
    offs[i] = o;
    cursor[i] = o;
  }
}

__global__ void fill_kernel(const int* __restrict__ recv, int* __restrict__ cursor,
                            int* __restrict__ sorted, int M_) {
  int m = blockIdx.x * 256 + threadIdx.x;
  if (m < M_) {
    int pos = atomicAdd(&cursor[recv[m]], 1);
    sorted[pos] = m;
  }
}

// ---------------------------------------------------------------------------
// Fused edge attention + aggregate: one wave per receiver node.
// Q/K/V bf16 (16 B/lane gathers, 1024 B per row, fully coalesced);
// math fp32; agg written bf16. Global max/+3 shift cancels in normalization.
// ---------------------------------------------------------------------------
__global__ __launch_bounds__(256)
void attn_kernel(const __hip_bfloat16* __restrict__ Q, const __hip_bfloat16* __restrict__ K,
                 const __hip_bfloat16* __restrict__ V, const int* __restrict__ senders,
                 const int* __restrict__ sorted, const int* __restrict__ offs,
                 float* __restrict__ attbuf, __hip_bfloat16* __restrict__ agg, int n) {
  const int lane = threadIdx.x & 63;
  const int wid  = threadIdx.x >> 6;
  const int r = blockIdx.x * 4 + wid;
  if (r >= n) return;
  const int start = offs[r];
  const int end   = offs[r + 1];

  uint4 qr = *(const uint4*)(Q + (size_t)r * DMODEL + lane * 8);
  float q[8] = {bflo(qr.x), bfhi(qr.x), bflo(qr.y), bfhi(qr.y),
                bflo(qr.z), bfhi(qr.z), bflo(qr.w), bfhi(qr.w)};

  float ssum = 0.f;
  for (int e = start; e < end; ++e) {
    int m = sorted[e];
    int s = senders[m];
    uint4 kr = *(const uint4*)(K + (size_t)s * DMODEL + lane * 8);
    float p = q[0] * bflo(kr.x) + q[1] * bfhi(kr.x)
            + q[2] * bflo(kr.y) + q[3] * bfhi(kr.y)
            + q[4] * bflo(kr.z) + q[5] * bfhi(kr.z)
            + q[6] * bflo(kr.w) + q[7] * bfhi(kr.w);
    p += __shfl_xor(p, 1);
    p += __shfl_xor(p, 2);
    p += __shfl_xor(p, 4);          // 8-lane head group all hold the dot
    float w = expf(p * 0.125f);     // 1/sqrt(DK)
    ssum += w;
    if ((lane & 7) == 0) attbuf[(size_t)e * 8 + (lane >> 3)] = w;
  }
  const float inv = (end > start) ? 1.0f / ssum : 0.f;

  float acc[8] = {};
  for (int e = start; e < end; ++e) {
    int m = sorted[e];
    int s = senders[m];
    float w = attbuf[(size_t)e * 8 + (lane >> 3)] * inv;
    uint4 vr = *(const uint4*)(V + (size_t)s * DMODEL + lane * 8);
    acc[0] += w * bflo(vr.x); acc[1] += w * bfhi(vr.x);
    acc[2] += w * bflo(vr.y); acc[3] += w * bfhi(vr.y);
    acc[4] += w * bflo(vr.z); acc[5] += w * bfhi(vr.z);
    acc[6] += w * bflo(vr.w); acc[7] += w * bfhi(vr.w);
  }
  union { ushort4 u; __hip_bfloat16 h[4]; } o0, o1;
  o0.h[0] = __float2bfloat16(acc[0]); o0.h[1] = __float2bfloat16(acc[1]);
  o0.h[2] = __float2bfloat16(acc[2]); o0.h[3] = __float2bfloat16(acc[3]);
  o1.h[0] = __float2bfloat16(acc[4]); o1.h[1] = __float2bfloat16(acc[5]);
  o1.h[2] = __float2bfloat16(acc[6]); o1.h[3] = __float2bfloat16(acc[7]);
  *(ushort4*)(agg + (size_t)r * DMODEL + lane * 8)     = o0.u;
  *(ushort4*)(agg + (size_t)r * DMODEL + lane * 8 + 4) = o1.u;
}

// ---------------------------------------------------------------------------
// Launch
// ---------------------------------------------------------------------------
extern "C" void kernel_launch(void* const* d_in, const int* in_sizes, int n_in,
                              void* d_out, int out_size, void* d_ws, size_t ws_size,
                              hipStream_t stream) {
  const float* x    = (const float*)d_in[0];
  const int*   eidx = (const int*)d_in[1];
  const float* Wk   = (const float*)d_in[2];
  const float* bk   = (const float*)d_in[3];
  const float* Wq   = (const float*)d_in[4];
  const float* bq   = (const float*)d_in[5];
  const float* Wv   = (const float*)d_in[6];
  const float* bv   = (const float*)d_in[7];
  const float* Wff  = (const float*)d_in[8];
  const float* bff  = (const float*)d_in[9];
  float* out = (float*)d_out;

  const int N_ = in_sizes[0] / DMODEL;   // 25000
  const int M_ = in_sizes[1] / 2;        // 150000
  const int* senders = eidx;             // edge_index[0]
  const int* recv    = eidx + M_;        // edge_index[1]

  // workspace: bf16 Q|K|V|x|agg|Wt[4], fp32 att, ints
  __hip_bfloat16* Qb = (__hip_bfloat16*)d_ws;
  __hip_bfloat16* Kb   = Qb + (size_t)N_ * DMODEL;
  __hip_bfloat16* Vb   = Kb + (size_t)N_ * DMODEL;
  __hip_bfloat16* xb   = Vb + (size_t)N_ * DMODEL;
  __hip_bfloat16* aggb = xb + (size_t)N_ * DMODEL;
  __hip_bfloat16* Wtk  = aggb + (size_t)N_ * DMODEL;
  __hip_bfloat16* Wtq  = Wtk + DMODEL * DMODEL;
  __hip_bfloat16* Wtv  = Wtq + DMODEL * DMODEL;
  __hip_bfloat16* Wtff = Wtv + DMODEL * DMODEL;
  float* attb = (float*)(Wtff + DMODEL * DMODEL);
  int* deg    = (int*)(attb + (size_t)M_ * 8);
  int* offs   = deg + N_;
  int* cursor = offs + N_ + 1;
  int* sorted = cursor + N_;
  int* bsum   = sorted + M_;
  int* bbase  = bsum + 64;

  const int nblk = (N_ + 1023) / 1024;   // 25 (<=64 for single-wave mid scan)

  // conversions
  int nx = N_ * DMODEL;
  cvt_kernel<<<(nx / 4 + 255) / 256, 256, 0, stream>>>(x, xb, nx);
  wt_kernel<<<dim3(8, 8, 4), 256, 0, stream>>>(Wk, Wq, Wv, Wff, Wtk, Wtq, Wtv, Wtff);

  // CSR build
  hipMemsetAsync(deg, 0, N_ * sizeof(int), stream);
  hist_kernel<<<(M_ + 255) / 256, 256, 0, stream>>>(recv, deg, M_);
  scan_block<<<nblk, 256, 0, stream>>>(deg, offs, bsum, N_);
  scan_mid<<<1, 64, 0, stream>>>(bsum, bbase, nblk, offs, N_);
  scan_add<<<(N_ + 255) / 256, 256, 0, stream>>>(offs, bbase, cursor, N_);
  fill_kernel<<<(M_ + 255) / 256, 256, 0, stream>>>(recv, cursor, sorted, M_);

  // projections (bf16 MFMA, bf16 outputs)
  dim3 ggrid(DMODEL / 128, (N_ + 127) / 128);
  gemm_bf16<true><<<ggrid, 256, 0, stream>>>(xb, Wtk, bk, Kb, N_);
  gemm_bf16<true><<<ggrid, 256, 0, stream>>>(xb, Wtq, bq, Qb, N_);
  gemm_bf16<true><<<ggrid, 256, 0, stream>>>(xb, Wtv, bv, Vb, N_);

  // fused edge softmax + aggregate
  attn_kernel<<<(N_ + 3) / 4, 256, 0, stream>>>(Qb, Kb, Vb, senders, sorted, offs,
                                                attb, aggb, N_);

  // output projection (fp32 out)
  gemm_bf16<false><<<ggrid, 256, 0, stream>>>(aggb, Wtff, bff, out, N_);
}

// Round 4
// 360.803 us; speedup vs baseline: 3.0085x; 1.1131x over previous
//
#include <hip/hip_runtime.h>
#include <hip/hip_bf16.h>

#define DMODEL 512   // D = H*DK = H*DV = 512

typedef __attribute__((ext_vector_type(8))) short bf16x8;
typedef __attribute__((ext_vector_type(4))) float f32x4;

__device__ inline void gload_lds16(const void* g, void* s) {
  __builtin_amdgcn_global_load_lds((const __attribute__((address_space(1))) void*)g,
                                   (__attribute__((address_space(3))) void*)s, 16, 0, 0);
}

__device__ inline float bflo(unsigned u) {
  union { float f; unsigned u; } c; c.u = u << 16; return c.f;
}
__device__ inline float bfhi(unsigned u) {
  union { float f; unsigned u; } c; c.u = u & 0xffff0000u; return c.f;
}

// ---------------------------------------------------------------------------
// bf16 MFMA GEMM: C[Mrows x ncols] = A_bf16[Mrows x 512] @ Wt_bf16[ncols x 512]^T + bias
// 128x128 tile, 4 waves, 4x4 16x16x32 MFMA per wave, global_load_lds width=16,
// LDS in fragment order (lane-linear subtiles) -> conflict-free ds_read_b128.
// ---------------------------------------------------------------------------
template <bool OUT_BF16>
__global__ __launch_bounds__(256)
void gemm_bf16(const __hip_bfloat16* __restrict__ A, const __hip_bfloat16* __restrict__ Wt,
               const float* __restrict__ bias, void* __restrict__ Cv, int Mrows, int ncols) {
  __shared__ __align__(16) short sA[16 * 512];
  __shared__ __align__(16) short sB[16 * 512];
  const int t = threadIdx.x;
  const int lane = t & 63;
  const int wid = t >> 6;
  const int wrow = wid >> 1, wcol = wid & 1;
  const int row0 = blockIdx.y * 128;
  const int col0 = blockIdx.x * 128;
  const int l15 = lane & 15, lq = lane >> 4;

  f32x4 acc[4][4] = {};

  for (int k0 = 0; k0 < DMODEL; k0 += 64) {
#pragma unroll
    for (int j = 0; j < 4; ++j) {
      int i = wid * 4 + j;
      int mt = i & 7, s = i >> 3;
      int ak = k0 + s * 32 + lq * 8;
      int arow = row0 + mt * 16 + l15;
      arow = min(arow, Mrows - 1);
      gload_lds16(A + (size_t)arow * DMODEL + ak, &sA[i * 512]);
      int brow = col0 + mt * 16 + l15;
      gload_lds16(Wt + (size_t)brow * DMODEL + ak, &sB[i * 512]);
    }
    __syncthreads();

#pragma unroll
    for (int s = 0; s < 2; ++s) {
      bf16x8 af[4], bfr[4];
#pragma unroll
      for (int m = 0; m < 4; ++m)
        af[m] = *(const bf16x8*)&sA[(s * 8 + wrow * 4 + m) * 512 + lane * 8];
#pragma unroll
      for (int n = 0; n < 4; ++n)
        bfr[n] = *(const bf16x8*)&sB[(s * 8 + wcol * 4 + n) * 512 + lane * 8];
#pragma unroll
      for (int m = 0; m < 4; ++m)
#pragma unroll
        for (int n = 0; n < 4; ++n)
          acc[m][n] = __builtin_amdgcn_mfma_f32_16x16x32_bf16(af[m], bfr[n], acc[m][n], 0, 0, 0);
    }
    __syncthreads();
  }

  // epilogue: C/D layout col=lane&15, row=quad*4+reg
#pragma unroll
  for (int m = 0; m < 4; ++m) {
#pragma unroll
    for (int n = 0; n < 4; ++n) {
      int col = col0 + wcol * 64 + n * 16 + l15;
      float bv = bias[col];
#pragma unroll
      for (int i = 0; i < 4; ++i) {
        int row = row0 + wrow * 64 + m * 16 + lq * 4 + i;
        if (row < Mrows) {
          float v = acc[m][n][i] + bv;
          if (OUT_BF16)
            ((__hip_bfloat16*)Cv)[(size_t)row * ncols + col] = __float2bfloat16(v);
          else
            ((float*)Cv)[(size_t)row * ncols + col] = v;
        }
      }
    }
  }
}

// ---------------------------------------------------------------------------
// fp32 -> bf16 convert (x)
// ---------------------------------------------------------------------------
__global__ void cvt_kernel(const float* __restrict__ src, __hip_bfloat16* __restrict__ dst, int n) {
  int i = (blockIdx.x * 256 + threadIdx.x) * 4;
  if (i < n) {
    float4 v = *(const float4*)(src + i);
    union { ushort4 u; __hip_bfloat16 h[4]; } o;
    o.h[0] = __float2bfloat16(v.x);
    o.h[1] = __float2bfloat16(v.y);
    o.h[2] = __float2bfloat16(v.z);
    o.h[3] = __float2bfloat16(v.w);
    *(ushort4*)(dst + i) = o.u;
  }
}

// ---------------------------------------------------------------------------
// 512x512 weight transpose + convert, batched over 4 weights via blockIdx.z
// ---------------------------------------------------------------------------
__global__ __launch_bounds__(256)
void wt_kernel(const float* __restrict__ W0, const float* __restrict__ W1,
               const float* __restrict__ W2, const float* __restrict__ W3,
               __hip_bfloat16* __restrict__ T0, __hip_bfloat16* __restrict__ T1,
               __hip_bfloat16* __restrict__ T2, __hip_bfloat16* __restrict__ T3) {
  const float* W; __hip_bfloat16* T;
  switch (blockIdx.z) {
    case 0: W = W0; T = T0; break;
    case 1: W = W1; T = T1; break;
    case 2: W = W2; T = T2; break;
    default: W = W3; T = T3; break;
  }
  __shared__ float tile[64][65];
  const int kb = blockIdx.y * 64, nb = blockIdx.x * 64;
  const int tx = threadIdx.x & 63, ty = threadIdx.x >> 6;
  for (int r = ty; r < 64; r += 4)
    tile[r][tx] = W[(size_t)(kb + r) * DMODEL + nb + tx];
  __syncthreads();
  for (int r = ty; r < 64; r += 4)
    T[(size_t)(nb + r) * DMODEL + kb + tx] = __float2bfloat16(tile[tx][r]);
}

// bias concat [bk | bq | bv]
__global__ void bias_kernel(const float* __restrict__ bk, const float* __restrict__ bq,
                            const float* __restrict__ bv, float* __restrict__ o) {
  int i = blockIdx.x * 256 + threadIdx.x;
  if (i < 512) o[i] = bk[i];
  else if (i < 1024) o[i] = bq[i - 512];
  else if (i < 1536) o[i] = bv[i - 1024];
}

// ---------------------------------------------------------------------------
// CSR build: histogram + parallel 3-phase scan + fill (stores SENDER directly)
// ---------------------------------------------------------------------------
__global__ void hist_kernel(const int* __restrict__ recv, int* __restrict__ deg, int M_) {
  int m = blockIdx.x * 256 + threadIdx.x;
  if (m < M_) atomicAdd(&deg[recv[m]], 1);
}

__global__ __launch_bounds__(256)
void scan_block(const int* __restrict__ deg, int* __restrict__ offs,
                int* __restrict__ bsum, int n) {
  __shared__ int sd[256];
  const int t = threadIdx.x;
  const int base = blockIdx.x * 1024;
  int v[4], s = 0;
#pragma unroll
  for (int j = 0; j < 4; ++j) {
    int idx = base + t * 4 + j;
    v[j] = (idx < n) ? deg[idx] : 0;
    s += v[j];
  }
  sd[t] = s;
  __syncthreads();
  for (int off = 1; off < 256; off <<= 1) {
    int x = (t >= off) ? sd[t - off] : 0;
    __syncthreads();
    sd[t] += x;
    __syncthreads();
  }
  int run = sd[t] - s;
#pragma unroll
  for (int j = 0; j < 4; ++j) {
    int idx = base + t * 4 + j;
    if (idx < n) offs[idx] = run;
    run += v[j];
  }
  if (t == 255) bsum[blockIdx.x] = sd[255];
}

__global__ void scan_mid(const int* __restrict__ bsum, int* __restrict__ bbase,
                         int nb, int* __restrict__ offs, int n) {
  int t = threadIdx.x;
  int x = (t < nb) ? bsum[t] : 0;
  int v = x;
  for (int off = 1; off < 64; off <<= 1) {
    int y = __shfl_up(v, off);
    if (t >= off) v += y;
  }
  if (t < nb) bbase[t] = v - x;
  if (t == nb - 1) offs[n] = v;
}

__global__ void scan_add(int* __restrict__ offs, const int* __restrict__ bbase,
                         int* __restrict__ cursor, int n) {
  int i = blockIdx.x * 256 + threadIdx.x;
  if (i < n) {
    int o = offs[i] + bbase[i >> 10];
    offs[i] = o;
    cursor[i] = o;
  }
}

__global__ void fill_kernel(const int* __restrict__ senders, const int* __restrict__ recv,
                            int* __restrict__ cursor, int* __restrict__ sidx, int M_) {
  int m = blockIdx.x * 256 + threadIdx.x;
  if (m < M_) {
    int pos = atomicAdd(&cursor[recv[m]], 1);
    sidx[pos] = senders[m];    // sender id directly: one less indirection in attn
  }
}

// ---------------------------------------------------------------------------
// Fused edge attention + aggregate, SINGLE PASS: one wave per receiver.
// QKV packed per row: [K(0:512) | Q(512:1024) | V(1024:1536)] bf16, stride 1536.
// acc accumulates unnormalized w*V; scale by 1/ssum at the end (normalization
// is a per-(receiver,head) scalar, so this is exact up to fp ordering).
// Edge loop unrolled x2: 4x16B gathers in flight per iteration.
// ---------------------------------------------------------------------------
__global__ __launch_bounds__(256)
void attn_kernel(const __hip_bfloat16* __restrict__ QKV, const int* __restrict__ sidx,
                 const int* __restrict__ offs, __hip_bfloat16* __restrict__ agg, int n) {
  const int lane = threadIdx.x & 63;
  const int wid  = threadIdx.x >> 6;
  const int r = blockIdx.x * 4 + wid;
  if (r >= n) return;
  const int start = offs[r];
  const int end   = offs[r + 1];

  uint4 qr = *(const uint4*)(QKV + (size_t)r * 1536 + 512 + lane * 8);
  float q[8] = {bflo(qr.x), bfhi(qr.x), bflo(qr.y), bfhi(qr.y),
                bflo(qr.z), bfhi(qr.z), bflo(qr.w), bfhi(qr.w)};

  float ssum = 0.f;
  float acc[8] = {};
  int e = start;
  for (; e + 2 <= end; e += 2) {
    int s0 = sidx[e], s1 = sidx[e + 1];
    const __hip_bfloat16* p0 = QKV + (size_t)s0 * 1536 + lane * 8;
    const __hip_bfloat16* p1 = QKV + (size_t)s1 * 1536 + lane * 8;
    uint4 k0 = *(const uint4*)p0;
    uint4 v0 = *(const uint4*)(p0 + 1024);
    uint4 k1 = *(const uint4*)p1;
    uint4 v1 = *(const uint4*)(p1 + 1024);
    float d0 = q[0] * bflo(k0.x) + q[1] * bfhi(k0.x) + q[2] * bflo(k0.y) + q[3] * bfhi(k0.y)
             + q[4] * bflo(k0.z) + q[5] * bfhi(k0.z) + q[6] * bflo(k0.w) + q[7] * bfhi(k0.w);
    float d1 = q[0] * bflo(k1.x) + q[1] * bfhi(k1.x) + q[2] * bflo(k1.y) + q[3] * bfhi(k1.y)
             + q[4] * bflo(k1.z) + q[5] * bfhi(k1.z) + q[6] * bflo(k1.w) + q[7] * bfhi(k1.w);
    d0 += __shfl_xor(d0, 1); d1 += __shfl_xor(d1, 1);
    d0 += __shfl_xor(d0, 2); d1 += __shfl_xor(d1, 2);
    d0 += __shfl_xor(d0, 4); d1 += __shfl_xor(d1, 4);
    float w0 = expf(d0 * 0.125f), w1 = expf(d1 * 0.125f);
    ssum += w0 + w1;
    acc[0] += w0 * bflo(v0.x) + w1 * bflo(v1.x);
    acc[1] += w0 * bfhi(v0.x) + w1 * bfhi(v1.x);
    acc[2] += w0 * bflo(v0.y) + w1 * bflo(v1.y);
    acc[3] += w0 * bfhi(v0.y) + w1 * bfhi(v1.y);
    acc[4] += w0 * bflo(v0.z) + w1 * bflo(v1.z);
    acc[5] += w0 * bfhi(v0.z) + w1 * bfhi(v1.z);
    acc[6] += w0 * bflo(v0.w) + w1 * bflo(v1.w);
    acc[7] += w0 * bfhi(v0.w) + w1 * bfhi(v1.w);
  }
  if (e < end) {
    int s0 = sidx[e];
    const __hip_bfloat16* p0 = QKV + (size_t)s0 * 1536 + lane * 8;
    uint4 k0 = *(const uint4*)p0;
    uint4 v0 = *(const uint4*)(p0 + 1024);
    float d0 = q[0] * bflo(k0.x) + q[1] * bfhi(k0.x) + q[2] * bflo(k0.y) + q[3] * bfhi(k0.y)
             + q[4] * bflo(k0.z) + q[5] * bfhi(k0.z) + q[6] * bflo(k0.w) + q[7] * bfhi(k0.w);
    d0 += __shfl_xor(d0, 1);
    d0 += __shfl_xor(d0, 2);
    d0 += __shfl_xor(d0, 4);
    float w0 = expf(d0 * 0.125f);
    ssum += w0;
    acc[0] += w0 * bflo(v0.x); acc[1] += w0 * bfhi(v0.x);
    acc[2] += w0 * bflo(v0.y); acc[3] += w0 * bfhi(v0.y);
    acc[4] += w0 * bflo(v0.z); acc[5] += w0 * bfhi(v0.z);
    acc[6] += w0 * bflo(v0.w); acc[7] += w0 * bfhi(v0.w);
  }
  const float inv = (end > start) ? 1.0f / ssum : 0.f;
  union { ushort4 u; __hip_bfloat16 h[4]; } o0, o1;
  o0.h[0] = __float2bfloat16(acc[0] * inv); o0.h[1] = __float2bfloat16(acc[1] * inv);
  o0.h[2] = __float2bfloat16(acc[2] * inv); o0.h[3] = __float2bfloat16(acc[3] * inv);
  o1.h[0] = __float2bfloat16(acc[4] * inv); o1.h[1] = __float2bfloat16(acc[5] * inv);
  o1.h[2] = __float2bfloat16(acc[6] * inv); o1.h[3] = __float2bfloat16(acc[7] * inv);
  *(ushort4*)(agg + (size_t)r * DMODEL + lane * 8)     = o0.u;
  *(ushort4*)(agg + (size_t)r * DMODEL + lane * 8 + 4) = o1.u;
}

// ---------------------------------------------------------------------------
// Launch
// ---------------------------------------------------------------------------
extern "C" void kernel_launch(void* const* d_in, const int* in_sizes, int n_in,
                              void* d_out, int out_size, void* d_ws, size_t ws_size,
                              hipStream_t stream) {
  const float* x    = (const float*)d_in[0];
  const int*   eidx = (const int*)d_in[1];
  const float* Wk   = (const float*)d_in[2];
  const float* bk   = (const float*)d_in[3];
  const float* Wq   = (const float*)d_in[4];
  const float* bq   = (const float*)d_in[5];
  const float* Wv   = (const float*)d_in[6];
  const float* bv   = (const float*)d_in[7];
  const float* Wff  = (const float*)d_in[8];
  const float* bff  = (const float*)d_in[9];
  float* out = (float*)d_out;

  const int N_ = in_sizes[0] / DMODEL;   // 25000
  const int M_ = in_sizes[1] / 2;        // 150000
  const int* senders = eidx;             // edge_index[0]
  const int* recv    = eidx + M_;        // edge_index[1]

  // workspace: QKV (N x 1536 bf16) | xb | agg | WtQKV(3) | Wtff | bqkv | ints
  __hip_bfloat16* QKVb = (__hip_bfloat16*)d_ws;
  __hip_bfloat16* xb   = QKVb + (size_t)N_ * 1536;
  __hip_bfloat16* aggb = xb + (size_t)N_ * DMODEL;
  __hip_bfloat16* WtQKV = aggb + (size_t)N_ * DMODEL;   // rows: [K|Q|V]
  __hip_bfloat16* Wtff  = WtQKV + 3 * DMODEL * DMODEL;
  float* bqkv = (float*)(Wtff + DMODEL * DMODEL);
  int* deg    = (int*)(bqkv + 1536);
  int* offs   = deg + N_;
  int* cursor = offs + N_ + 1;
  int* sidx   = cursor + N_;
  int* bsum   = sidx + M_;
  int* bbase  = bsum + 64;

  const int nblk = (N_ + 1023) / 1024;   // 25 (<=64 for single-wave mid scan)

  // conversions
  int nx = N_ * DMODEL;
  cvt_kernel<<<(nx / 4 + 255) / 256, 256, 0, stream>>>(x, xb, nx);
  wt_kernel<<<dim3(8, 8, 4), 256, 0, stream>>>(
      Wk, Wq, Wv, Wff,
      WtQKV, WtQKV + DMODEL * DMODEL, WtQKV + 2 * DMODEL * DMODEL, Wtff);
  bias_kernel<<<6, 256, 0, stream>>>(bk, bq, bv, bqkv);

  // CSR build
  hipMemsetAsync(deg, 0, N_ * sizeof(int), stream);
  hist_kernel<<<(M_ + 255) / 256, 256, 0, stream>>>(recv, deg, M_);
  scan_block<<<nblk, 256, 0, stream>>>(deg, offs, bsum, N_);
  scan_mid<<<1, 64, 0, stream>>>(bsum, bbase, nblk, offs, N_);
  scan_add<<<(N_ + 255) / 256, 256, 0, stream>>>(offs, bbase, cursor, N_);
  fill_kernel<<<(M_ + 255) / 256, 256, 0, stream>>>(senders, recv, cursor, sidx, M_);

  // fused QKV projection: C is N x 1536 packed [K|Q|V]
  gemm_bf16<true><<<dim3(1536 / 128, (N_ + 127) / 128), 256, 0, stream>>>(
      xb, WtQKV, bqkv, QKVb, N_, 1536);

  // fused single-pass edge softmax + aggregate
  attn_kernel<<<(N_ + 3) / 4, 256, 0, stream>>>(QKVb, sidx, offs, aggb, N_);

  // output projection (fp32 out)
  gemm_bf16<false><<<dim3(DMODEL / 128, (N_ + 127) / 128), 256, 0, stream>>>(
      aggb, Wtff, bff, out, N_, DMODEL);
}

// Round 5
// 333.748 us; speedup vs baseline: 3.2524x; 1.0811x over previous
//
#include <hip/hip_runtime.h>
#include <hip/hip_bf16.h>

#define DMODEL 512   // D = H*DK = H*DV = 512

typedef __attribute__((ext_vector_type(8))) short bf16x8;
typedef __attribute__((ext_vector_type(4))) float f32x4;

__device__ inline void gload_lds16(const void* g, void* s) {
  __builtin_amdgcn_global_load_lds((const __attribute__((address_space(1))) void*)g,
                                   (__attribute__((address_space(3))) void*)s, 16, 0, 0);
}

__device__ inline float bflo(unsigned u) {
  union { float f; unsigned u; } c; c.u = u << 16; return c.f;
}
__device__ inline float bfhi(unsigned u) {
  union { float f; unsigned u; } c; c.u = u & 0xffff0000u; return c.f;
}

// ---------------------------------------------------------------------------
// Persistent-stripe bf16 MFMA GEMM.
// Block = (g, stripe): owns 64 output cols x K=512 of W, resident in LDS
// (64 KB, loaded ONCE -> one barrier per block total). 8 waves free-run over
// M with no further sync. A is pre-permuted into MFMA-fragment-linear layout
// xp[t][c][lane][8] (t = 16-row tile, c = 32-k chunk) so each A fragment is
// one coalesced global_load_dwordx4 per lane, straight to registers.
// Per wave: 4 m-tiles (64 rows) x 4 n-tiles (64 cols); per c-iter:
// 4 A loads (1-deep prefetch) + 4 ds_read_b128 + 16 MFMA.
// ---------------------------------------------------------------------------
template <bool OUT_BF16>
__global__ __launch_bounds__(512, 2)
void gemm_stripe(const __hip_bfloat16* __restrict__ Ap,   // padded, xp layout
                 const __hip_bfloat16* __restrict__ Wp,   // 32768 elems / stripe
                 const float* __restrict__ bias, void* __restrict__ Cv,
                 int Nrows, int ncols, int nquads, int G) {
  __shared__ __align__(16) short sB[32768];   // 64 KB
  const int tid = threadIdx.x;
  const int lane = tid & 63, w = tid >> 6;
  const int g = blockIdx.x, stripe = blockIdx.y;
  const int col0 = stripe * 64;
  const __hip_bfloat16* Ws = Wp + (size_t)stripe * 32768;

  // load B stripe into LDS: 8 rounds x 512 thr x 16 B, wave-contiguous
#pragma unroll
  for (int i = 0; i < 8; ++i)
    gload_lds16(Ws + (size_t)(i * 512 + tid) * 8, &sB[(i * 512 + tid) * 8]);
  __syncthreads();

  const int l15 = lane & 15, lq = lane >> 4;

  for (int q = g * 8 + w; q < nquads; q += G * 8) {
    f32x4 acc[4][4] = {};
    const __hip_bfloat16* Abase = Ap + (size_t)q * 32768 + lane * 8;
    bf16x8 a_cur[4], a_nxt[4];
#pragma unroll
    for (int m = 0; m < 4; ++m)
      a_cur[m] = *(const bf16x8*)(Abase + m * 8192);

#pragma unroll 1
    for (int c = 0; c < 16; ++c) {
      if (c < 15) {
#pragma unroll
        for (int m = 0; m < 4; ++m)
          a_nxt[m] = *(const bf16x8*)(Abase + m * 8192 + (c + 1) * 512);
      }
#pragma unroll
      for (int n = 0; n < 4; ++n) {
        bf16x8 bf = *(const bf16x8*)&sB[((n * 16 + c) * 64 + lane) * 8];
#pragma unroll
        for (int m = 0; m < 4; ++m)
          acc[m][n] = __builtin_amdgcn_mfma_f32_16x16x32_bf16(a_cur[m], bf, acc[m][n], 0, 0, 0);
      }
      if (c < 15) {
#pragma unroll
        for (int m = 0; m < 4; ++m) a_cur[m] = a_nxt[m];
      }
    }

    // epilogue: C/D layout col=lane&15, row=quad*4+reg
#pragma unroll
    for (int m = 0; m < 4; ++m) {
      int rowb = q * 64 + m * 16;
#pragma unroll
      for (int n = 0; n < 4; ++n) {
        int col = col0 + n * 16 + l15;
        float bv = bias[col];
#pragma unroll
        for (int i = 0; i < 4; ++i) {
          int row = rowb + lq * 4 + i;
          if (row < Nrows) {
            float v = acc[m][n][i] + bv;
            if (OUT_BF16)
              ((__hip_bfloat16*)Cv)[(size_t)row * ncols + col] = __float2bfloat16(v);
            else
              ((float*)Cv)[(size_t)row * ncols + col] = v;
          }
        }
      }
    }
  }
}

// ---------------------------------------------------------------------------
// fp32 x -> bf16 xp permute: xp[t][c][lp][8] with lp = q*16 + (r&15),
// q = (k%32)/8, c = k/32. One thread per (row, 8-k block). Pads with zeros.
// ---------------------------------------------------------------------------
__global__ void cvtp_kernel(const float* __restrict__ x, __hip_bfloat16* __restrict__ xp,
                            int Nrows, int NpadRows) {
  int tid = blockIdx.x * 256 + threadIdx.x;
  int r = tid >> 6, kb = tid & 63;
  if (r >= NpadRows) return;
  int t = r >> 4, c = kb >> 2, qq = kb & 3, lp = qq * 16 + (r & 15);
  __hip_bfloat16* dst = xp + (size_t)t * 8192 + c * 512 + lp * 8;
  union { ushort4 u[2]; __hip_bfloat16 h[8]; } o;
#pragma unroll
  for (int j = 0; j < 8; ++j) o.h[j] = __float2bfloat16(0.f);
  if (r < Nrows) {
    float4 v0 = *(const float4*)(x + (size_t)r * DMODEL + kb * 8);
    float4 v1 = *(const float4*)(x + (size_t)r * DMODEL + kb * 8 + 4);
    o.h[0] = __float2bfloat16(v0.x); o.h[1] = __float2bfloat16(v0.y);
    o.h[2] = __float2bfloat16(v0.z); o.h[3] = __float2bfloat16(v0.w);
    o.h[4] = __float2bfloat16(v1.x); o.h[5] = __float2bfloat16(v1.y);
    o.h[6] = __float2bfloat16(v1.z); o.h[7] = __float2bfloat16(v1.w);
  }
  *(ushort4*)dst = o.u[0];
  *(ushort4*)(dst + 4) = o.u[1];
}

// ---------------------------------------------------------------------------
// Weight permute: Wp[stripe][n][c][l][8] = W[c*32+(l>>4)*8+j][stripe*64+n*16+(l&15)]
// 32 stripes total: 0-7 Wk, 8-15 Wq, 16-23 Wv (-> Wp_qkv), 24-31 Wff (-> Wp_ff).
// ---------------------------------------------------------------------------
__global__ __launch_bounds__(256)
void wp_kernel(const float* __restrict__ Wk, const float* __restrict__ Wq,
               const float* __restrict__ Wv, const float* __restrict__ Wff,
               __hip_bfloat16* __restrict__ Wp_qkv, __hip_bfloat16* __restrict__ Wp_ff) {
  int c = blockIdx.x;        // 0..15
  int S = blockIdx.y;        // 0..31
  const float* W; __hip_bfloat16* dst;
  if (S < 8)       { W = Wk;  dst = Wp_qkv + (size_t)S * 32768; }
  else if (S < 16) { W = Wq;  dst = Wp_qkv + (size_t)S * 32768; }
  else if (S < 24) { W = Wv;  dst = Wp_qkv + (size_t)S * 32768; }
  else             { W = Wff; dst = Wp_ff + (size_t)(S - 24) * 32768; }
  int colbase = (S & 7) * 64;
  __shared__ float tile[32][64];
  for (int idx = threadIdx.x; idx < 2048; idx += 256) {
    int r = idx >> 6, col = idx & 63;
    tile[r][col] = W[(size_t)(c * 32 + r) * DMODEL + colbase + col];
  }
  __syncthreads();
  int n = threadIdx.x >> 6, l = threadIdx.x & 63;
  union { ushort4 u[2]; __hip_bfloat16 h[8]; } o;
#pragma unroll
  for (int j = 0; j < 8; ++j)
    o.h[j] = __float2bfloat16(tile[(l >> 4) * 8 + j][n * 16 + (l & 15)]);
  __hip_bfloat16* p = dst + ((size_t)(n * 16 + c) * 64 + l) * 8;
  *(ushort4*)p = o.u[0];
  *(ushort4*)(p + 4) = o.u[1];
}

// bias concat [bk | bq | bv]
__global__ void bias_kernel(const float* __restrict__ bk, const float* __restrict__ bq,
                            const float* __restrict__ bv, float* __restrict__ o) {
  int i = blockIdx.x * 256 + threadIdx.x;
  if (i < 512) o[i] = bk[i];
  else if (i < 1024) o[i] = bq[i - 512];
  else if (i < 1536) o[i] = bv[i - 1024];
}

// ---------------------------------------------------------------------------
// CSR build: histogram + parallel 3-phase scan + fill (stores SENDER directly)
// ---------------------------------------------------------------------------
__global__ void hist_kernel(const int* __restrict__ recv, int* __restrict__ deg, int M_) {
  int m = blockIdx.x * 256 + threadIdx.x;
  if (m < M_) atomicAdd(&deg[recv[m]], 1);
}

__global__ __launch_bounds__(256)
void scan_block(const int* __restrict__ deg, int* __restrict__ offs,
                int* __restrict__ bsum, int n) {
  __shared__ int sd[256];
  const int t = threadIdx.x;
  const int base = blockIdx.x * 1024;
  int v[4], s = 0;
#pragma unroll
  for (int j = 0; j < 4; ++j) {
    int idx = base + t * 4 + j;
    v[j] = (idx < n) ? deg[idx] : 0;
    s += v[j];
  }
  sd[t] = s;
  __syncthreads();
  for (int off = 1; off < 256; off <<= 1) {
    int x = (t >= off) ? sd[t - off] : 0;
    __syncthreads();
    sd[t] += x;
    __syncthreads();
  }
  int run = sd[t] - s;
#pragma unroll
  for (int j = 0; j < 4; ++j) {
    int idx = base + t * 4 + j;
    if (idx < n) offs[idx] = run;
    run += v[j];
  }
  if (t == 255) bsum[blockIdx.x] = sd[255];
}

__global__ void scan_mid(const int* __restrict__ bsum, int* __restrict__ bbase,
                         int nb, int* __restrict__ offs, int n) {
  int t = threadIdx.x;
  int x = (t < nb) ? bsum[t] : 0;
  int v = x;
  for (int off = 1; off < 64; off <<= 1) {
    int y = __shfl_up(v, off);
    if (t >= off) v += y;
  }
  if (t < nb) bbase[t] = v - x;
  if (t == nb - 1) offs[n] = v;
}

__global__ void scan_add(int* __restrict__ offs, const int* __restrict__ bbase,
                         int* __restrict__ cursor, int n) {
  int i = blockIdx.x * 256 + threadIdx.x;
  if (i < n) {
    int o = offs[i] + bbase[i >> 10];
    offs[i] = o;
    cursor[i] = o;
  }
}

__global__ void fill_kernel(const int* __restrict__ senders, const int* __restrict__ recv,
                            int* __restrict__ cursor, int* __restrict__ sidx, int M_) {
  int m = blockIdx.x * 256 + threadIdx.x;
  if (m < M_) {
    int pos = atomicAdd(&cursor[recv[m]], 1);
    sidx[pos] = senders[m];
  }
}

// ---------------------------------------------------------------------------
// Fused edge attention + aggregate, single pass, one wave per receiver.
// QKV row-major [K|Q|V] stride 1536 bf16. agg written DIRECTLY in xp
// (fragment-linear) layout for the out-GEMM.
// ---------------------------------------------------------------------------
__global__ __launch_bounds__(256)
void attn_kernel(const __hip_bfloat16* __restrict__ QKV, const int* __restrict__ sidx,
                 const int* __restrict__ offs, __hip_bfloat16* __restrict__ aggp, int n) {
  const int lane = threadIdx.x & 63;
  const int wid  = threadIdx.x >> 6;
  const int r = blockIdx.x * 4 + wid;
  if (r >= n) return;
  const int start = offs[r];
  const int end   = offs[r + 1];

  uint4 qr = *(const uint4*)(QKV + (size_t)r * 1536 + 512 + lane * 8);
  float q[8] = {bflo(qr.x), bfhi(qr.x), bflo(qr.y), bfhi(qr.y),
                bflo(qr.z), bfhi(qr.z), bflo(qr.w), bfhi(qr.w)};

  float ssum = 0.f;
  float acc[8] = {};
  int e = start;
  for (; e + 2 <= end; e += 2) {
    int s0 = sidx[e], s1 = sidx[e + 1];
    const __hip_bfloat16* p0 = QKV + (size_t)s0 * 1536 + lane * 8;
    const __hip_bfloat16* p1 = QKV + (size_t)s1 * 1536 + lane * 8;
    uint4 k0 = *(const uint4*)p0;
    uint4 v0 = *(const uint4*)(p0 + 1024);
    uint4 k1 = *(const uint4*)p1;
    uint4 v1 = *(const uint4*)(p1 + 1024);
    float d0 = q[0] * bflo(k0.x) + q[1] * bfhi(k0.x) + q[2] * bflo(k0.y) + q[3] * bfhi(k0.y)
             + q[4] * bflo(k0.z) + q[5] * bfhi(k0.z) + q[6] * bflo(k0.w) + q[7] * bfhi(k0.w);
    float d1 = q[0] * bflo(k1.x) + q[1] * bfhi(k1.x) + q[2] * bflo(k1.y) + q[3] * bfhi(k1.y)
             + q[4] * bflo(k1.z) + q[5] * bfhi(k1.z) + q[6] * bflo(k1.w) + q[7] * bfhi(k1.w);
    d0 += __shfl_xor(d0, 1); d1 += __shfl_xor(d1, 1);
    d0 += __shfl_xor(d0, 2); d1 += __shfl_xor(d1, 2);
    d0 += __shfl_xor(d0, 4); d1 += __shfl_xor(d1, 4);
    float w0 = expf(d0 * 0.125f), w1 = expf(d1 * 0.125f);
    ssum += w0 + w1;
    acc[0] += w0 * bflo(v0.x) + w1 * bflo(v1.x);
    acc[1] += w0 * bfhi(v0.x) + w1 * bfhi(v1.x);
    acc[2] += w0 * bflo(v0.y) + w1 * bflo(v1.y);
    acc[3] += w0 * bfhi(v0.y) + w1 * bfhi(v1.y);
    acc[4] += w0 * bflo(v0.z) + w1 * bflo(v1.z);
    acc[5] += w0 * bfhi(v0.z) + w1 * bfhi(v1.z);
    acc[6] += w0 * bflo(v0.w) + w1 * bflo(v1.w);
    acc[7] += w0 * bfhi(v0.w) + w1 * bfhi(v1.w);
  }
  if (e < end) {
    int s0 = sidx[e];
    const __hip_bfloat16* p0 = QKV + (size_t)s0 * 1536 + lane * 8;
    uint4 k0 = *(const uint4*)p0;
    uint4 v0 = *(const uint4*)(p0 + 1024);
    float d0 = q[0] * bflo(k0.x) + q[1] * bfhi(k0.x) + q[2] * bflo(k0.y) + q[3] * bfhi(k0.y)
             + q[4] * bflo(k0.z) + q[5] * bfhi(k0.z) + q[6] * bflo(k0.w) + q[7] * bfhi(k0.w);
    d0 += __shfl_xor(d0, 1);
    d0 += __shfl_xor(d0, 2);
    d0 += __shfl_xor(d0, 4);
    float w0 = expf(d0 * 0.125f);
    ssum += w0;
    acc[0] += w0 * bflo(v0.x); acc[1] += w0 * bfhi(v0.x);
    acc[2] += w0 * bflo(v0.y); acc[3] += w0 * bfhi(v0.y);
    acc[4] += w0 * bflo(v0.z); acc[5] += w0 * bfhi(v0.z);
    acc[6] += w0 * bflo(v0.w); acc[7] += w0 * bfhi(v0.w);
  }
  const float inv = (end > start) ? 1.0f / ssum : 0.f;
  union { ushort4 u[2]; __hip_bfloat16 h[8]; } o;
#pragma unroll
  for (int j = 0; j < 8; ++j) o.h[j] = __float2bfloat16(acc[j] * inv);
  // xp layout: lane holds k=lane*8..+7 -> c=lane>>2, q=lane&3, lp=q*16+(r&15)
  int t = r >> 4, c = lane >> 2, qq = lane & 3, lp = qq * 16 + (r & 15);
  __hip_bfloat16* dst = aggp + (size_t)t * 8192 + c * 512 + lp * 8;
  *(ushort4*)dst = o.u[0];
  *(ushort4*)(dst + 4) = o.u[1];
}

// ---------------------------------------------------------------------------
// Launch
// ---------------------------------------------------------------------------
extern "C" void kernel_launch(void* const* d_in, const int* in_sizes, int n_in,
                              void* d_out, int out_size, void* d_ws, size_t ws_size,
                              hipStream_t stream) {
  const float* x    = (const float*)d_in[0];
  const int*   eidx = (const int*)d_in[1];
  const float* Wk   = (const float*)d_in[2];
  const float* bk   = (const float*)d_in[3];
  const float* Wq   = (const float*)d_in[4];
  const float* bq   = (const float*)d_in[5];
  const float* Wv   = (const float*)d_in[6];
  const float* bv   = (const float*)d_in[7];
  const float* Wff  = (const float*)d_in[8];
  const float* bff  = (const float*)d_in[9];
  float* out = (float*)d_out;

  const int N_ = in_sizes[0] / DMODEL;   // 25000
  const int M_ = in_sizes[1] / 2;        // 150000
  const int* senders = eidx;             // edge_index[0]
  const int* recv    = eidx + M_;        // edge_index[1]

  const int T16 = (N_ + 15) / 16;        // 16-row tiles
  const int Q4  = (T16 + 3) / 4;         // 64-row quads
  const int Npad = Q4 * 64;              // padded rows

  // workspace: xp | QKVb | aggp | Wp_qkv | Wp_ff | bqkv | ints
  __hip_bfloat16* xp    = (__hip_bfloat16*)d_ws;
  __hip_bfloat16* QKVb  = xp + (size_t)Npad * DMODEL;
  __hip_bfloat16* aggp  = QKVb + (size_t)N_ * 1536;
  __hip_bfloat16* Wp_qkv = aggp + (size_t)Npad * DMODEL;
  __hip_bfloat16* Wp_ff  = Wp_qkv + (size_t)24 * 32768;
  float* bqkv = (float*)(Wp_ff + (size_t)8 * 32768);
  int* deg    = (int*)(bqkv + 1536);
  int* offs   = deg + N_;
  int* cursor = offs + N_ + 1;
  int* sidx   = cursor + N_;
  int* bsum   = sidx + M_;
  int* bbase  = bsum + 64;

  const int nblk = (N_ + 1023) / 1024;   // <=64 for single-wave mid scan

  // conversions / permutes
  cvtp_kernel<<<(Npad * 64 + 255) / 256, 256, 0, stream>>>(x, xp, N_, Npad);
  wp_kernel<<<dim3(16, 32), 256, 0, stream>>>(Wk, Wq, Wv, Wff, Wp_qkv, Wp_ff);
  bias_kernel<<<6, 256, 0, stream>>>(bk, bq, bv, bqkv);

  // CSR build
  hipMemsetAsync(deg, 0, N_ * sizeof(int), stream);
  hist_kernel<<<(M_ + 255) / 256, 256, 0, stream>>>(recv, deg, M_);
  scan_block<<<nblk, 256, 0, stream>>>(deg, offs, bsum, N_);
  scan_mid<<<1, 64, 0, stream>>>(bsum, bbase, nblk, offs, N_);
  scan_add<<<(N_ + 255) / 256, 256, 0, stream>>>(offs, bbase, cursor, N_);
  fill_kernel<<<(M_ + 255) / 256, 256, 0, stream>>>(senders, recv, cursor, sidx, M_);

  // fused QKV projection: 24 stripes x G blocks, out row-major [K|Q|V] x 1536
  const int Gq = 21;   // 24*21 = 504 blocks ~= 2/CU
  gemm_stripe<true><<<dim3(Gq, 24), 512, 0, stream>>>(xp, Wp_qkv, bqkv, QKVb,
                                                      N_, 1536, Q4, Gq);

  // fused single-pass edge softmax + aggregate (writes aggp in xp layout)
  attn_kernel<<<(N_ + 3) / 4, 256, 0, stream>>>(QKVb, sidx, offs, aggp, N_);

  // output projection: 8 stripes x G blocks, fp32 row-major out
  const int Go = 63;   // 8*63 = 504 blocks
  gemm_stripe<false><<<dim3(Go, 8), 512, 0, stream>>>(aggp, Wp_ff, bff, out,
                                                      N_, DMODEL, Q4, Go);
}

// Round 6
// 311.470 us; speedup vs baseline: 3.4850x; 1.0715x over previous
//
#include <hip/hip_runtime.h>
#include <hip/hip_bf16.h>

#define DMODEL 512   // D = H*DK = H*DV = 512

typedef __attribute__((ext_vector_type(8))) short bf16x8;
typedef __attribute__((ext_vector_type(4))) float f32x4;

__device__ inline void gload_lds16(const void* g, void* s) {
  __builtin_amdgcn_global_load_lds((const __attribute__((address_space(1))) void*)g,
                                   (__attribute__((address_space(3))) void*)s, 16, 0, 0);
}

__device__ inline float bflo(unsigned u) {
  union { float f; unsigned u; } c; c.u = u << 16; return c.f;
}
__device__ inline float bfhi(unsigned u) {
  union { float f; unsigned u; } c; c.u = u & 0xffff0000u; return c.f;
}

// ---------------------------------------------------------------------------
// Quad-persistent bf16 MFMA GEMM, W-streamed.
// Block = one 64-row quad: A-quad (64 KB, fragment-linear xp layout) staged to
// LDS ONCE (single barrier), then 8 waves free-run. W is NOT staged: every
// block streams the same W fragments from global -> L2-resident on all XCDs
// (W is 0.5-1.5 MB). A is read from HBM exactly once across the whole GEMM.
// Wave w owns n-tiles [w*NT, (w+1)*NT), processed in groups of 4 (64 cols)
// with acc[4][4] in regs; per c-iter: 4 ds_read_b128 (A) + 4 global dwordx4
// (B, 1-deep prefetch, ~310 cyc of MFMA covers ~200 cyc L2 latency) + 16 MFMA.
// ---------------------------------------------------------------------------
template <bool OUT_BF16, int NT>
__global__ __launch_bounds__(512, 2)
void gemm_quad(const __hip_bfloat16* __restrict__ Ap,   // xp layout, 32768/quad
               const __hip_bfloat16* __restrict__ Wp,   // [nt][c][lane][8]
               const float* __restrict__ bias, void* __restrict__ Cv,
               int Nrows, int ncols) {
  __shared__ __align__(16) short sA[32768];   // 64 KB: one quad of A
  const int tid = threadIdx.x;
  const int lane = tid & 63, w = tid >> 6;
  const int q = blockIdx.x;
  const __hip_bfloat16* Aq = Ap + (size_t)q * 32768;

#pragma unroll
  for (int i = 0; i < 8; ++i)
    gload_lds16(Aq + (size_t)(i * 512 + tid) * 8, &sA[(i * 512 + tid) * 8]);
  __syncthreads();

  const int l15 = lane & 15, lq = lane >> 4;

#pragma unroll 1
  for (int gs = 0; gs < NT / 4; ++gs) {
    const int ntb = w * NT + gs * 4;
    const __hip_bfloat16* Wb = Wp + (size_t)ntb * 16 * 512 + lane * 8;
    f32x4 acc[4][4] = {};
    bf16x8 b_cur[4], b_nxt[4];
#pragma unroll
    for (int n = 0; n < 4; ++n)
      b_cur[n] = *(const bf16x8*)(Wb + (size_t)(n * 16) * 512);

#pragma unroll 1
    for (int c = 0; c < 16; ++c) {
      if (c < 15) {
#pragma unroll
        for (int n = 0; n < 4; ++n)
          b_nxt[n] = *(const bf16x8*)(Wb + (size_t)(n * 16 + c + 1) * 512);
      }
#pragma unroll
      for (int m = 0; m < 4; ++m) {
        bf16x8 af = *(const bf16x8*)&sA[(m * 16 + c) * 512 + lane * 8];
#pragma unroll
        for (int n = 0; n < 4; ++n)
          acc[m][n] = __builtin_amdgcn_mfma_f32_16x16x32_bf16(af, b_cur[n], acc[m][n], 0, 0, 0);
      }
      if (c < 15) {
#pragma unroll
        for (int n = 0; n < 4; ++n) b_cur[n] = b_nxt[n];
      }
    }

    // epilogue: C/D layout col=lane&15, row=quad*4+reg
#pragma unroll
    for (int m = 0; m < 4; ++m) {
      int rowb = q * 64 + m * 16;
#pragma unroll
      for (int n = 0; n < 4; ++n) {
        int col = (ntb + n) * 16 + l15;
        float bv = bias[col];
#pragma unroll
        for (int i = 0; i < 4; ++i) {
          int row = rowb + lq * 4 + i;
          if (row < Nrows) {
            float v = acc[m][n][i] + bv;
            if (OUT_BF16)
              ((__hip_bfloat16*)Cv)[(size_t)row * ncols + col] = __float2bfloat16(v);
            else
              ((float*)Cv)[(size_t)row * ncols + col] = v;
          }
        }
      }
    }
  }
}

// ---------------------------------------------------------------------------
// fp32 x -> bf16 xp permute: xp[t][c][lp][8], lp = q*16 + (r&15). Zero-pads.
// ---------------------------------------------------------------------------
__global__ void cvtp_kernel(const float* __restrict__ x, __hip_bfloat16* __restrict__ xp,
                            int Nrows, int NpadRows) {
  int tid = blockIdx.x * 256 + threadIdx.x;
  int r = tid >> 6, kb = tid & 63;
  if (r >= NpadRows) return;
  int t = r >> 4, c = kb >> 2, qq = kb & 3, lp = qq * 16 + (r & 15);
  __hip_bfloat16* dst = xp + (size_t)t * 8192 + c * 512 + lp * 8;
  union { ushort4 u[2]; __hip_bfloat16 h[8]; } o;
#pragma unroll
  for (int j = 0; j < 8; ++j) o.h[j] = __float2bfloat16(0.f);
  if (r < Nrows) {
    float4 v0 = *(const float4*)(x + (size_t)r * DMODEL + kb * 8);
    float4 v1 = *(const float4*)(x + (size_t)r * DMODEL + kb * 8 + 4);
    o.h[0] = __float2bfloat16(v0.x); o.h[1] = __float2bfloat16(v0.y);
    o.h[2] = __float2bfloat16(v0.z); o.h[3] = __float2bfloat16(v0.w);
    o.h[4] = __float2bfloat16(v1.x); o.h[5] = __float2bfloat16(v1.y);
    o.h[6] = __float2bfloat16(v1.z); o.h[7] = __float2bfloat16(v1.w);
  }
  *(ushort4*)dst = o.u[0];
  *(ushort4*)(dst + 4) = o.u[1];
}

// ---------------------------------------------------------------------------
// Weight permute: Wp[nt][c][l][8] with nt = stripe*4 + nlocal (so col = nt*16
// + (l&15), k = c*32 + (l>>4)*8 + j). Stripes 0-23 -> Wp_qkv, 24-31 -> Wp_ff.
// ---------------------------------------------------------------------------
__global__ __launch_bounds__(256)
void wp_kernel(const float* __restrict__ Wk, const float* __restrict__ Wq,
               const float* __restrict__ Wv, const float* __restrict__ Wff,
               __hip_bfloat16* __restrict__ Wp_qkv, __hip_bfloat16* __restrict__ Wp_ff) {
  int c = blockIdx.x;        // 0..15
  int S = blockIdx.y;        // 0..31
  const float* W; __hip_bfloat16* dst;
  if (S < 8)       { W = Wk;  dst = Wp_qkv + (size_t)S * 32768; }
  else if (S < 16) { W = Wq;  dst = Wp_qkv + (size_t)S * 32768; }
  else if (S < 24) { W = Wv;  dst = Wp_qkv + (size_t)S * 32768; }
  else             { W = Wff; dst = Wp_ff + (size_t)(S - 24) * 32768; }
  int colbase = (S & 7) * 64;
  __shared__ float tile[32][64];
  for (int idx = threadIdx.x; idx < 2048; idx += 256) {
    int r = idx >> 6, col = idx & 63;
    tile[r][col] = W[(size_t)(c * 32 + r) * DMODEL + colbase + col];
  }
  __syncthreads();
  int n = threadIdx.x >> 6, l = threadIdx.x & 63;
  union { ushort4 u[2]; __hip_bfloat16 h[8]; } o;
#pragma unroll
  for (int j = 0; j < 8; ++j)
    o.h[j] = __float2bfloat16(tile[(l >> 4) * 8 + j][n * 16 + (l & 15)]);
  __hip_bfloat16* p = dst + ((size_t)(n * 16 + c) * 64 + l) * 8;
  *(ushort4*)p = o.u[0];
  *(ushort4*)(p + 4) = o.u[1];
}

// bias concat [bk | bq | bv]
__global__ void bias_kernel(const float* __restrict__ bk, const float* __restrict__ bq,
                            const float* __restrict__ bv, float* __restrict__ o) {
  int i = blockIdx.x * 256 + threadIdx.x;
  if (i < 512) o[i] = bk[i];
  else if (i < 1024) o[i] = bq[i - 512];
  else if (i < 1536) o[i] = bv[i - 1024];
}

// ---------------------------------------------------------------------------
// CSR build: histogram + parallel 3-phase scan + fill (stores SENDER directly)
// ---------------------------------------------------------------------------
__global__ void hist_kernel(const int* __restrict__ recv, int* __restrict__ deg, int M_) {
  int m = blockIdx.x * 256 + threadIdx.x;
  if (m < M_) atomicAdd(&deg[recv[m]], 1);
}

__global__ __launch_bounds__(256)
void scan_block(const int* __restrict__ deg, int* __restrict__ offs,
                int* __restrict__ bsum, int n) {
  __shared__ int sd[256];
  const int t = threadIdx.x;
  const int base = blockIdx.x * 1024;
  int v[4], s = 0;
#pragma unroll
  for (int j = 0; j < 4; ++j) {
    int idx = base + t * 4 + j;
    v[j] = (idx < n) ? deg[idx] : 0;
    s += v[j];
  }
  sd[t] = s;
  __syncthreads();
  for (int off = 1; off < 256; off <<= 1) {
    int x = (t >= off) ? sd[t - off] : 0;
    __syncthreads();
    sd[t] += x;
    __syncthreads();
  }
  int run = sd[t] - s;
#pragma unroll
  for (int j = 0; j < 4; ++j) {
    int idx = base + t * 4 + j;
    if (idx < n) offs[idx] = run;
    run += v[j];
  }
  if (t == 255) bsum[blockIdx.x] = sd[255];
}

__global__ void scan_mid(const int* __restrict__ bsum, int* __restrict__ bbase,
                         int nb, int* __restrict__ offs, int n) {
  int t = threadIdx.x;
  int x = (t < nb) ? bsum[t] : 0;
  int v = x;
  for (int off = 1; off < 64; off <<= 1) {
    int y = __shfl_up(v, off);
    if (t >= off) v += y;
  }
  if (t < nb) bbase[t] = v - x;
  if (t == nb - 1) offs[n] = v;
}

__global__ void scan_add(int* __restrict__ offs, const int* __restrict__ bbase,
                         int* __restrict__ cursor, int n) {
  int i = blockIdx.x * 256 + threadIdx.x;
  if (i < n) {
    int o = offs[i] + bbase[i >> 10];
    offs[i] = o;
    cursor[i] = o;
  }
}

__global__ void fill_kernel(const int* __restrict__ senders, const int* __restrict__ recv,
                            int* __restrict__ cursor, int* __restrict__ sidx, int M_) {
  int m = blockIdx.x * 256 + threadIdx.x;
  if (m < M_) {
    int pos = atomicAdd(&cursor[recv[m]], 1);
    sidx[pos] = senders[m];
  }
}

// ---------------------------------------------------------------------------
// Fused edge attention + aggregate, single pass, one wave per receiver.
// QKV row-major [K|Q|V] stride 1536 bf16. agg written directly in xp layout.
// ---------------------------------------------------------------------------
__global__ __launch_bounds__(256)
void attn_kernel(const __hip_bfloat16* __restrict__ QKV, const int* __restrict__ sidx,
                 const int* __restrict__ offs, __hip_bfloat16* __restrict__ aggp, int n) {
  const int lane = threadIdx.x & 63;
  const int wid  = threadIdx.x >> 6;
  const int r = blockIdx.x * 4 + wid;
  if (r >= n) return;
  const int start = offs[r];
  const int end   = offs[r + 1];

  uint4 qr = *(const uint4*)(QKV + (size_t)r * 1536 + 512 + lane * 8);
  float q[8] = {bflo(qr.x), bfhi(qr.x), bflo(qr.y), bfhi(qr.y),
                bflo(qr.z), bfhi(qr.z), bflo(qr.w), bfhi(qr.w)};

  float ssum = 0.f;
  float acc[8] = {};
  int e = start;
  for (; e + 2 <= end; e += 2) {
    int s0 = sidx[e], s1 = sidx[e + 1];
    const __hip_bfloat16* p0 = QKV + (size_t)s0 * 1536 + lane * 8;
    const __hip_bfloat16* p1 = QKV + (size_t)s1 * 1536 + lane * 8;
    uint4 k0 = *(const uint4*)p0;
    uint4 v0 = *(const uint4*)(p0 + 1024);
    uint4 k1 = *(const uint4*)p1;
    uint4 v1 = *(const uint4*)(p1 + 1024);
    float d0 = q[0] * bflo(k0.x) + q[1] * bfhi(k0.x) + q[2] * bflo(k0.y) + q[3] * bfhi(k0.y)
             + q[4] * bflo(k0.z) + q[5] * bfhi(k0.z) + q[6] * bflo(k0.w) + q[7] * bfhi(k0.w);
    float d1 = q[0] * bflo(k1.x) + q[1] * bfhi(k1.x) + q[2] * bflo(k1.y) + q[3] * bfhi(k1.y)
             + q[4] * bflo(k1.z) + q[5] * bfhi(k1.z) + q[6] * bflo(k1.w) + q[7] * bfhi(k1.w);
    d0 += __shfl_xor(d0, 1); d1 += __shfl_xor(d1, 1);
    d0 += __shfl_xor(d0, 2); d1 += __shfl_xor(d1, 2);
    d0 += __shfl_xor(d0, 4); d1 += __shfl_xor(d1, 4);
    float w0 = expf(d0 * 0.125f), w1 = expf(d1 * 0.125f);
    ssum += w0 + w1;
    acc[0] += w0 * bflo(v0.x) + w1 * bflo(v1.x);
    acc[1] += w0 * bfhi(v0.x) + w1 * bfhi(v1.x);
    acc[2] += w0 * bflo(v0.y) + w1 * bflo(v1.y);
    acc[3] += w0 * bfhi(v0.y) + w1 * bfhi(v1.y);
    acc[4] += w0 * bflo(v0.z) + w1 * bflo(v1.z);
    acc[5] += w0 * bfhi(v0.z) + w1 * bfhi(v1.z);
    acc[6] += w0 * bflo(v0.w) + w1 * bflo(v1.w);
    acc[7] += w0 * bfhi(v0.w) + w1 * bfhi(v1.w);
  }
  if (e < end) {
    int s0 = sidx[e];
    const __hip_bfloat16* p0 = QKV + (size_t)s0 * 1536 + lane * 8;
    uint4 k0 = *(const uint4*)p0;
    uint4 v0 = *(const uint4*)(p0 + 1024);
    float d0 = q[0] * bflo(k0.x) + q[1] * bfhi(k0.x) + q[2] * bflo(k0.y) + q[3] * bfhi(k0.y)
             + q[4] * bflo(k0.z) + q[5] * bfhi(k0.z) + q[6] * bflo(k0.w) + q[7] * bfhi(k0.w);
    d0 += __shfl_xor(d0, 1);
    d0 += __shfl_xor(d0, 2);
    d0 += __shfl_xor(d0, 4);
    float w0 = expf(d0 * 0.125f);
    ssum += w0;
    acc[0] += w0 * bflo(v0.x); acc[1] += w0 * bfhi(v0.x);
    acc[2] += w0 * bflo(v0.y); acc[3] += w0 * bfhi(v0.y);
    acc[4] += w0 * bflo(v0.z); acc[5] += w0 * bfhi(v0.z);
    acc[6] += w0 * bflo(v0.w); acc[7] += w0 * bfhi(v0.w);
  }
  const float inv = (end > start) ? 1.0f / ssum : 0.f;
  union { ushort4 u[2]; __hip_bfloat16 h[8]; } o;
#pragma unroll
  for (int j = 0; j < 8; ++j) o.h[j] = __float2bfloat16(acc[j] * inv);
  // xp layout: lane holds k=lane*8..+7 -> c=lane>>2, q=lane&3, lp=q*16+(r&15)
  int t = r >> 4, c = lane >> 2, qq = lane & 3, lp = qq * 16 + (r & 15);
  __hip_bfloat16* dst = aggp + (size_t)t * 8192 + c * 512 + lp * 8;
  *(ushort4*)dst = o.u[0];
  *(ushort4*)(dst + 4) = o.u[1];
}

// ---------------------------------------------------------------------------
// Launch
// ---------------------------------------------------------------------------
extern "C" void kernel_launch(void* const* d_in, const int* in_sizes, int n_in,
                              void* d_out, int out_size, void* d_ws, size_t ws_size,
                              hipStream_t stream) {
  const float* x    = (const float*)d_in[0];
  const int*   eidx = (const int*)d_in[1];
  const float* Wk   = (const float*)d_in[2];
  const float* bk   = (const float*)d_in[3];
  const float* Wq   = (const float*)d_in[4];
  const float* bq   = (const float*)d_in[5];
  const float* Wv   = (const float*)d_in[6];
  const float* bv   = (const float*)d_in[7];
  const float* Wff  = (const float*)d_in[8];
  const float* bff  = (const float*)d_in[9];
  float* out = (float*)d_out;

  const int N_ = in_sizes[0] / DMODEL;   // 25000
  const int M_ = in_sizes[1] / 2;        // 150000
  const int* senders = eidx;             // edge_index[0]
  const int* recv    = eidx + M_;        // edge_index[1]

  const int T16 = (N_ + 15) / 16;        // 16-row tiles
  const int Q4  = (T16 + 3) / 4;         // 64-row quads (= grid of gemm_quad)
  const int Npad = Q4 * 64;

  // workspace: xp | QKVb | aggp | Wp_qkv | Wp_ff | bqkv | ints
  __hip_bfloat16* xp    = (__hip_bfloat16*)d_ws;
  __hip_bfloat16* QKVb  = xp + (size_t)Npad * DMODEL;
  __hip_bfloat16* aggp  = QKVb + (size_t)N_ * 1536;
  __hip_bfloat16* Wp_qkv = aggp + (size_t)Npad * DMODEL;
  __hip_bfloat16* Wp_ff  = Wp_qkv + (size_t)24 * 32768;
  float* bqkv = (float*)(Wp_ff + (size_t)8 * 32768);
  int* deg    = (int*)(bqkv + 1536);
  int* offs   = deg + N_;
  int* cursor = offs + N_ + 1;
  int* sidx   = cursor + N_;
  int* bsum   = sidx + M_;
  int* bbase  = bsum + 64;

  const int nblk = (N_ + 1023) / 1024;   // <=64 for single-wave mid scan

  // conversions / permutes
  cvtp_kernel<<<(Npad * 64 + 255) / 256, 256, 0, stream>>>(x, xp, N_, Npad);
  wp_kernel<<<dim3(16, 32), 256, 0, stream>>>(Wk, Wq, Wv, Wff, Wp_qkv, Wp_ff);
  bias_kernel<<<6, 256, 0, stream>>>(bk, bq, bv, bqkv);

  // CSR build
  hipMemsetAsync(deg, 0, N_ * sizeof(int), stream);
  hist_kernel<<<(M_ + 255) / 256, 256, 0, stream>>>(recv, deg, M_);
  scan_block<<<nblk, 256, 0, stream>>>(deg, offs, bsum, N_);
  scan_mid<<<1, 64, 0, stream>>>(bsum, bbase, nblk, offs, N_);
  scan_add<<<(N_ + 255) / 256, 256, 0, stream>>>(offs, bbase, cursor, N_);
  fill_kernel<<<(M_ + 255) / 256, 256, 0, stream>>>(senders, recv, cursor, sidx, M_);

  // fused QKV projection: one block per quad, A-in-LDS, W streamed via L2
  gemm_quad<true, 12><<<Q4, 512, 0, stream>>>(xp, Wp_qkv, bqkv, QKVb, N_, 1536);

  // fused single-pass edge softmax + aggregate (writes aggp in xp layout)
  attn_kernel<<<(N_ + 3) / 4, 256, 0, stream>>>(QKVb, sidx, offs, aggp, N_);

  // output projection
  gemm_quad<false, 4><<<Q4, 512, 0, stream>>>(aggp, Wp_ff, bff, out, N_, DMODEL);
}